// Round 12
// baseline (1244.496 us; speedup 1.0000x reference)
//
#include <hip/hip_runtime.h>

// MyTransformer: 6-enc + 6-dec, S=1024, D=512, H=8x64, FF=2048.
// Round 11: weight GEMMs -> 128x64 tile (wave=32x64, 16 MFMA : 12 ds_read,
// 3-buf, 72KB, 2 blocks/CU); attn proj slabs bf16 (halve LN<8> traffic).
// Fused attn+proj; split-K FF2 + LN merge; 95 dispatches.

#define NLAY 6

typedef __attribute__((ext_vector_type(8))) short short8;
typedef __attribute__((ext_vector_type(4))) short short4v;
typedef __attribute__((ext_vector_type(4))) float f32x4;

typedef __attribute__((address_space(3))) short lds_short;
typedef __attribute__((address_space(1))) const unsigned short g_ushort;

__device__ __forceinline__ void gload16(const unsigned short* g, short* l) {
    __builtin_amdgcn_global_load_lds((g_ushort*)g, (lds_short*)l, 16, 0, 0);
}

__device__ __forceinline__ void waitvm(int n) {   // wave-uniform literal waits
    if (n == 0)      asm volatile("s_waitcnt vmcnt(0)" ::: "memory");
    else if (n == 4) asm volatile("s_waitcnt vmcnt(4)" ::: "memory");
    else if (n == 6) asm volatile("s_waitcnt vmcnt(6)" ::: "memory");
    else             asm volatile("s_waitcnt vmcnt(8)" ::: "memory");
}

__device__ inline unsigned short f2bu(float x) {
    unsigned u = __builtin_bit_cast(unsigned, x);
    unsigned r = (u + 0x7fffu + ((u >> 16) & 1u)) >> 16;   // RNE
    return (unsigned short)r;
}

__device__ inline float b2f(unsigned short u) {
    return __builtin_bit_cast(float, (unsigned)u << 16);
}

// ------------- fp32 -> bf16 weight cvt: flat balanced grid, 1 dispatch -------
struct WCvt {
    const float* src[10];
    unsigned short* dst[10];
    long cum[11];           // prefix sums in 8-element chunks
};

__global__ __launch_bounds__(256)
void f2ball_k(WCvt wc)
{
    const long total = wc.cum[10];
    for (long c = (long)blockIdx.x * 256 + threadIdx.x; c < total;
         c += (long)gridDim.x * 256) {
        int t = 0;
        #pragma unroll
        for (int i = 1; i < 10; ++i) if (c >= wc.cum[i]) t = i;
        const long o = (c - wc.cum[t]) * 8;
        const float* s = wc.src[t];
        unsigned short* d = wc.dst[t];
        const float4 a = *(const float4*)(s + o);
        const float4 b = *(const float4*)(s + o + 4);
        short8 v;
        v[0] = (short)f2bu(a.x); v[1] = (short)f2bu(a.y);
        v[2] = (short)f2bu(a.z); v[3] = (short)f2bu(a.w);
        v[4] = (short)f2bu(b.x); v[5] = (short)f2bu(b.y);
        v[6] = (short)f2bu(b.z); v[7] = (short)f2bu(b.w);
        *(short8*)(d + o) = v;
    }
}

__global__ __launch_bounds__(256)
void f2b_k(const float* __restrict__ s, unsigned short* __restrict__ d, long n)
{
    const long stride = (long)gridDim.x * 256;
    for (long i = (long)blockIdx.x * 256 + threadIdx.x; i * 8 < n; i += stride) {
        const long o = i * 8;
        const float4 a = *(const float4*)(s + o);
        const float4 b = *(const float4*)(s + o + 4);
        short8 v;
        v[0] = (short)f2bu(a.x); v[1] = (short)f2bu(a.y);
        v[2] = (short)f2bu(a.z); v[3] = (short)f2bu(a.w);
        v[4] = (short)f2bu(b.x); v[5] = (short)f2bu(b.y);
        v[6] = (short)f2bu(b.z); v[7] = (short)f2bu(b.w);
        *(short8*)(d + o) = v;
    }
}

// ------- weight GEMM: 128x64 tile, wave = 32x64, 3-buf gload_lds pipeline ----
// A: [M][K] bf16 (lda), B: [N][K] bf16 (ldb). 256 thr = 4 waves; wave w owns
// rows w*32..+32 x 64 cols: acc[2][4], 16 MFMA : 12 ds_read per K-step.
// LDS 72 KB -> 2 blocks/CU. Split-K via kz; A2 = merged QKV; VTp = V scatter.
template<bool RELU, bool OBF16>
__global__ __launch_bounds__(256)
void gemmT_k(const unsigned short* __restrict__ A,
             const unsigned short* __restrict__ A2, int a2_col, int lda,
             const unsigned short* __restrict__ B, int ldb,
             const float* __restrict__ bias,
             void* __restrict__ Cv, int ldc, long sC,
             int K, float alpha,
             unsigned short* __restrict__ VTp, int vt_col0, int kz)
{
    __shared__ __align__(16) short As[3][128 * 64];   // 48 KB
    __shared__ __align__(16) short Bs[3][64 * 64];    // 24 KB
    const int bz = blockIdx.z;
    const int m0 = blockIdx.y * 128;
    const int n0 = blockIdx.x * 64;
    if (A2 && n0 >= a2_col) A = A2;
    A += (long)bz * kz;
    B += (long)bz * kz;
    const int tid = threadIdx.x;
    const int w  = tid >> 6;
    const int l  = tid & 63;
    const int fr = l & 15;
    const int kc = l >> 4;

    f32x4 acc[2][4] = {};
    const int T = K >> 6;

    auto FILL = [&](int t, int buf) {
        const int k0 = t * 64;
        #pragma unroll
        for (int it = 0; it < 4; ++it) {       // A: wave's 32 rows (4 stripes of 8)
            const int row = w * 32 + it * 8 + (l >> 3);
            const int sl  = ((l & 7) ^ (row & 7)) * 8;
            gload16(A + (long)(m0 + row) * lda + k0 + sl,
                    &As[buf][(w * 32 + it * 8) * 64]);
        }
        #pragma unroll
        for (int it = 0; it < 2; ++it) {       // B: wave stages rows w*16..+16
            const int row = w * 16 + it * 8 + (l >> 3);
            const int sl  = ((l & 7) ^ (row & 7)) * 8;
            gload16(B + (long)(n0 + row) * ldb + k0 + sl,
                    &Bs[buf][(w * 16 + it * 8) * 64]);
        }
    };

    FILL(0, 0);
    if (T > 1) FILL(1, 1);
    for (int t = 0; t < T; ++t) {
        waitvm(t + 1 < T ? 6 : 0);
        __builtin_amdgcn_sched_barrier(0);
        __builtin_amdgcn_s_barrier();
        if (t + 2 < T) FILL(t + 2, (t + 2) % 3);
        const int cb = t % 3;
        #pragma unroll
        for (int ks = 0; ks < 2; ++ks) {
            const int sl = ((ks * 4 + kc) ^ (fr & 7)) * 8;
            short8 af[2], bf[4];
            #pragma unroll
            for (int r = 0; r < 2; ++r)
                af[r] = *(const short8*)&As[cb][(w * 32 + r * 16 + fr) * 64 + sl];
            #pragma unroll
            for (int c = 0; c < 4; ++c)
                bf[c] = *(const short8*)&Bs[cb][(c * 16 + fr) * 64 + sl];
            #pragma unroll
            for (int r = 0; r < 2; ++r)
                #pragma unroll
                for (int c = 0; c < 4; ++c)
                    acc[r][c] = __builtin_amdgcn_mfma_f32_16x16x32_bf16(af[r], bf[c], acc[r][c], 0, 0, 0);
        }
    }

    #pragma unroll
    for (int c = 0; c < 4; ++c) {
        const int n = n0 + c * 16 + fr;
        const float bv = bias ? bias[n] : 0.0f;
        const bool do_vt = (VTp != nullptr) && (n >= vt_col0);
        #pragma unroll
        for (int r = 0; r < 2; ++r) {
            #pragma unroll
            for (int i = 0; i < 4; ++i) {
                const long m = m0 + w * 32 + r * 16 + kc * 4 + i;
                float v = acc[r][c][i] * alpha + bv;
                if (RELU) v = fmaxf(v, 0.0f);
                if (OBF16) ((unsigned short*)Cv)[bz * sC + m * ldc + n] = f2bu(v);
                else       ((float*)Cv)[bz * sC + m * ldc + n] = v;
                if (do_vt) {
                    const int vc = n - vt_col0;
                    VTp[(long)(vc >> 6) * 65536 + (long)(vc & 63) * 1024 + m] = f2bu(v);
                }
            }
        }
    }
}

// ---------------- 64x64-tile GEMM (gram): 3-buf pipeline ---------------------
__global__ __launch_bounds__(256)
void gemm3_k(const unsigned short* __restrict__ A, int lda,
             const unsigned short* __restrict__ B, int ldb,
             float* __restrict__ C, int ldc, int K)
{
    __shared__ __align__(16) short As[3][4096];
    __shared__ __align__(16) short Bs[3][4096];
    const int m0 = blockIdx.y * 64;
    const int n0 = blockIdx.x * 64;
    const int tid = threadIdx.x;
    const int w  = tid >> 6;
    const int l  = tid & 63;
    const int fr = l & 15;
    const int kc = l >> 4;

    f32x4 acc[4] = {};
    const int T = K >> 6;

    auto FILL = [&](int t, int buf) {
        const int k0 = t * 64;
        #pragma unroll
        for (int it = 0; it < 2; ++it) {
            const int row = w * 16 + it * 8 + (l >> 3);
            const int sl  = ((l & 7) ^ (row & 7)) * 8;
            gload16(A + (long)(m0 + row) * lda + k0 + sl, &As[buf][(w * 16 + it * 8) * 64]);
            gload16(B + (long)(n0 + row) * ldb + k0 + sl, &Bs[buf][(w * 16 + it * 8) * 64]);
        }
    };

    FILL(0, 0);
    if (T > 1) FILL(1, 1);
    for (int t = 0; t < T; ++t) {
        waitvm(t + 1 < T ? 4 : 0);
        __builtin_amdgcn_sched_barrier(0);
        __builtin_amdgcn_s_barrier();
        if (t + 2 < T) FILL(t + 2, (t + 2) % 3);
        const int cb = t % 3;
        #pragma unroll
        for (int ks = 0; ks < 2; ++ks) {
            const int arow = w * 16 + fr;
            const short8 af = *(const short8*)&As[cb][arow * 64 + (((ks * 4 + kc) ^ (arow & 7)) * 8)];
            #pragma unroll
            for (int c = 0; c < 4; ++c) {
                const int brow = c * 16 + fr;
                const short8 bf = *(const short8*)&Bs[cb][brow * 64 + (((ks * 4 + kc) ^ (brow & 7)) * 8)];
                acc[c] = __builtin_amdgcn_mfma_f32_16x16x32_bf16(af, bf, acc[c], 0, 0, 0);
            }
        }
    }

    #pragma unroll
    for (int c = 0; c < 4; ++c) {
        const int n = n0 + c * 16 + fr;
        #pragma unroll
        for (int i = 0; i < 4; ++i) {
            const long m = m0 + w * 16 + kc * 4 + i;
            C[m * ldc + n] = acc[c][i];
        }
    }
}

// ------- fused attention + out-projection -> per-head bf16 slabs -------------
__global__ __launch_bounds__(128)
void attnp_k(const unsigned short* __restrict__ QKVb,   // [1024][1536]
             const unsigned short* __restrict__ VT,     // [8][64][1024]
             const unsigned short* __restrict__ wo,     // [512][512] bf16
             unsigned short* __restrict__ SLABb)        // 8 x [1024][512] bf16
{
    __shared__ __align__(16) short U[18432];   // 36 KB
    short* Ks = U;            // 2 x 4096
    short* Vs = U + 8192;     // 2 x 4096
    short* Ps = U + 16384;    // 2 x 1024
    const int qt = blockIdx.x;
    const int h  = blockIdx.y;
    const int tid = threadIdx.x;
    const int w  = tid >> 6;
    const int l  = tid & 63;
    const int fr = l & 15;
    const int kc = l >> 4;

    const int qrow = qt * 32 + w * 16 + fr;
    short8 qf[2];
    qf[0] = *(const short8*)(QKVb + (long)qrow * 1536 + h * 64 + kc * 8);
    qf[1] = *(const short8*)(QKVb + (long)qrow * 1536 + h * 64 + 32 + kc * 8);

    auto FILL = [&](int t, int buf) {
        const int kb = t * 64;
        #pragma unroll
        for (int it = 0; it < 4; ++it) {
            const int row = it * 16 + w * 8 + (l >> 3);
            const int sl  = ((l & 7) ^ (row & 7)) * 8;
            gload16(QKVb + (long)(kb + row) * 1536 + 512 + h * 64 + sl,
                    Ks + buf * 4096 + (it * 16 + w * 8) * 64);
            gload16(VT + (long)h * 65536 + (long)row * 1024 + kb + sl,
                    Vs + buf * 4096 + (it * 16 + w * 8) * 64);
        }
    };

    float m_i[4], l_i[4];
    f32x4 acc_o[4] = {};
    #pragma unroll
    for (int i = 0; i < 4; ++i) { m_i[i] = -1e30f; l_i[i] = 0.f; }

    short* ps = Ps + w * 1024;

    FILL(0, 0); FILL(1, 1);
    for (int t = 0; t < 16; ++t) {
        waitvm(t == 15 ? 0 : 8);
        __builtin_amdgcn_sched_barrier(0);
        __builtin_amdgcn_s_barrier();

        f32x4 sacc[4] = {};
        const int cb = t & 1;
        #pragma unroll
        for (int ks = 0; ks < 2; ++ks) {
            #pragma unroll
            for (int c = 0; c < 4; ++c) {
                const int krow = c * 16 + fr;
                const short8 kf = *(const short8*)(Ks + cb * 4096 + krow * 64 + (((ks * 4 + kc) ^ (krow & 7)) * 8));
                sacc[c] = __builtin_amdgcn_mfma_f32_16x16x32_bf16(qf[ks], kf, sacc[c], 0, 0, 0);
            }
        }

        float p[4][4];
        #pragma unroll
        for (int i = 0; i < 4; ++i) {
            float tm = fmaxf(fmaxf(sacc[0][i], sacc[1][i]), fmaxf(sacc[2][i], sacc[3][i]));
            #pragma unroll
            for (int off = 8; off; off >>= 1) tm = fmaxf(tm, __shfl_xor(tm, off));
            tm *= 0.125f;
            const float mn = fmaxf(m_i[i], tm);
            const float sc = __expf(m_i[i] - mn);
            m_i[i] = mn;
            float ts = 0.f;
            #pragma unroll
            for (int c = 0; c < 4; ++c) { p[c][i] = __expf(sacc[c][i] * 0.125f - mn); ts += p[c][i]; }
            #pragma unroll
            for (int off = 8; off; off >>= 1) ts += __shfl_xor(ts, off);
            l_i[i] = l_i[i] * sc + ts;
            #pragma unroll
            for (int c = 0; c < 4; ++c) acc_o[c][i] *= sc;
        }

        #pragma unroll
        for (int c = 0; c < 4; ++c) {
            const int col = c * 16 + fr;
            #pragma unroll
            for (int i = 0; i < 4; ++i) {
                const int row = kc * 4 + i;
                ps[row * 64 + (((col >> 3) ^ (row & 7)) * 8) + (col & 7)] = (short)f2bu(p[c][i]);
            }
        }
        short8 pf[2];
        pf[0] = *(const short8*)(ps + fr * 64 + ((kc ^ (fr & 7)) * 8));
        pf[1] = *(const short8*)(ps + fr * 64 + (((4 + kc) ^ (fr & 7)) * 8));

        #pragma unroll
        for (int ks = 0; ks < 2; ++ks) {
            #pragma unroll
            for (int c = 0; c < 4; ++c) {
                const int drow = c * 16 + fr;
                const short8 vf = *(const short8*)(Vs + cb * 4096 + drow * 64 + (((ks * 4 + kc) ^ (drow & 7)) * 8));
                acc_o[c] = __builtin_amdgcn_mfma_f32_16x16x32_bf16(pf[ks], vf, acc_o[c], 0, 0, 0);
            }
        }
        __builtin_amdgcn_s_barrier();
        if (t + 2 < 16) FILL(t + 2, (t + 2) & 1);
    }

    // -------- epilogue: O (regs) @ Wo_h^T -> per-head bf16 slab --------
    short* po = Ps + w * 1024;
    #pragma unroll
    for (int c = 0; c < 4; ++c) {
        const int col = c * 16 + fr;
        #pragma unroll
        for (int i = 0; i < 4; ++i) {
            const int r = kc * 4 + i;
            po[r * 64 + (((col >> 3) ^ (r & 7)) * 8) + (col & 7)] =
                (short)f2bu(acc_o[c][i] / l_i[i]);
        }
    }
    __syncthreads();

    short* Wos = U;    // reuse Ks region
    unsigned short* SLABh = SLABb + (long)h * 524288;
    const int orow = qt * 32 + w * 16;

    auto WSTAGE = [&](int c8, int buf) {
        const int n0c = c8 * 64;
        #pragma unroll
        for (int it = 0; it < 4; ++it) {
            const int rb  = w * 32 + it * 8;
            const int row = rb + (l >> 3);
            const int sl  = ((l & 7) ^ (row & 7)) * 8;
            gload16(wo + (long)(n0c + row) * 512 + h * 64 + sl, Wos + buf * 4096 + rb * 64);
        }
    };

    WSTAGE(0, 0);
    for (int c8 = 0; c8 < 8; ++c8) {
        if (c8) __syncthreads();
        if (c8 + 1 < 8) WSTAGE(c8 + 1, (c8 + 1) & 1);
        waitvm(c8 + 1 < 8 ? 4 : 0);
        __builtin_amdgcn_sched_barrier(0);
        __builtin_amdgcn_s_barrier();
        const int buf = c8 & 1;
        f32x4 a2[4] = {};
        #pragma unroll
        for (int ks = 0; ks < 2; ++ks) {
            const int q = ks * 4 + kc;
            const short8 af = *(const short8*)(po + fr * 64 + ((q ^ (fr & 7)) * 8));
            #pragma unroll
            for (int ct = 0; ct < 4; ++ct) {
                const int brn = ct * 16 + fr;
                const short8 bf = *(const short8*)(Wos + buf * 4096 + brn * 64 + ((q ^ (brn & 7)) * 8));
                a2[ct] = __builtin_amdgcn_mfma_f32_16x16x32_bf16(af, bf, a2[ct], 0, 0, 0);
            }
        }
        #pragma unroll
        for (int ct = 0; ct < 4; ++ct) {
            const int n = c8 * 64 + ct * 16 + fr;
            #pragma unroll
            for (int i = 0; i < 4; ++i)
                SLABh[(long)(orow + kc * 4 + i) * 512 + n] = f2bu(a2[ct][i]);
        }
    }
}

// ---- LayerNorm-as-merge: out = LN(x + sum_slabs + bias)*s + b ---------------
// SB16: slabs are bf16 (attn proj partials); else fp32 (FF2 split-K).
template<int NSLAB, bool SB16>
__global__ __launch_bounds__(256)
void ln_k(const float* __restrict__ x, const void* __restrict__ slab,
          const float* __restrict__ bias,
          const float* __restrict__ s, const float* __restrict__ b,
          float* __restrict__ out, unsigned short* __restrict__ outb)
{
    const int lane = threadIdx.x & 63;
    const int row  = (blockIdx.x << 2) + (threadIdx.x >> 6);
    const float* px = x + (long)row * 512;
    float v[8];
    float sum = 0.f;
    #pragma unroll
    for (int i = 0; i < 8; ++i) {
        const int j = lane + (i << 6);
        v[i] = px[j];
        #pragma unroll
        for (int t = 0; t < NSLAB; ++t) {
            if (SB16) v[i] += b2f(((const unsigned short*)slab)[(long)t * 524288 + (long)row * 512 + j]);
            else      v[i] += ((const float*)slab)[(long)t * 524288 + (long)row * 512 + j];
        }
        if (NSLAB > 0) v[i] += bias[j];
        sum += v[i];
    }
    #pragma unroll
    for (int off = 32; off; off >>= 1) sum += __shfl_xor(sum, off);
    const float m = sum * (1.0f / 512.0f);
    float s2 = 0.f;
    #pragma unroll
    for (int i = 0; i < 8; ++i) { const float d = v[i] - m; s2 += d * d; }
    #pragma unroll
    for (int off = 32; off; off >>= 1) s2 += __shfl_xor(s2, off);
    const float inv = rsqrtf(s2 * (1.0f / 512.0f) + 1e-5f);
    #pragma unroll
    for (int i = 0; i < 8; ++i) {
        const int j = lane + (i << 6);
        const float r = (v[i] - m) * inv * s[j] + b[j];
        out[(long)row * 512 + j] = r;
        if (outb) outb[(long)row * 512 + j] = f2bu(r);
    }
}

// -------- fused final LN + L2-normalize --------------------------------------
__global__ __launch_bounds__(256)
void lnl2_k(const float* __restrict__ x,
            const float* __restrict__ s, const float* __restrict__ b,
            float* __restrict__ out_attn, unsigned short* __restrict__ nb)
{
    const int lane = threadIdx.x & 63;
    const int row  = (blockIdx.x << 2) + (threadIdx.x >> 6);
    const float* px = x + (long)row * 512;
    float v[8];
    float sum = 0.f;
    #pragma unroll
    for (int i = 0; i < 8; ++i) { v[i] = px[lane + (i << 6)]; sum += v[i]; }
    #pragma unroll
    for (int off = 32; off; off >>= 1) sum += __shfl_xor(sum, off);
    const float m = sum * (1.0f / 512.0f);
    float s2 = 0.f;
    #pragma unroll
    for (int i = 0; i < 8; ++i) { const float d = v[i] - m; s2 += d * d; }
    #pragma unroll
    for (int off = 32; off; off >>= 1) s2 += __shfl_xor(s2, off);
    const float inv = rsqrtf(s2 * (1.0f / 512.0f) + 1e-5f);
    float nrm = 0.f;
    #pragma unroll
    for (int i = 0; i < 8; ++i) {
        const int j = lane + (i << 6);
        v[i] = (v[i] - m) * inv * s[j] + b[j];
        out_attn[(long)row * 512 + j] = v[i];
        nrm += v[i] * v[i];
    }
    #pragma unroll
    for (int off = 32; off; off >>= 1) nrm += __shfl_xor(nrm, off);
    const float rinv = rsqrtf(nrm);
    #pragma unroll
    for (int i = 0; i < 8; ++i)
        nb[(long)row * 512 + lane + (i << 6)] = f2bu(v[i] * rinv);
}

// -------- init: x -> MEMf, Yf (fp32) + MEMb, Yb (bf16) -----------------------
__global__ __launch_bounds__(256)
void init_k(const float* __restrict__ x, float* __restrict__ mf, float* __restrict__ yf,
            unsigned short* __restrict__ mb, unsigned short* __restrict__ yb)
{
    const long i = ((long)blockIdx.x * 256 + threadIdx.x) * 4;
    const float4 v = *(const float4*)(x + i);
    *(float4*)(mf + i) = v;
    *(float4*)(yf + i) = v;
    short4v s;
    s[0] = (short)f2bu(v.x); s[1] = (short)f2bu(v.y);
    s[2] = (short)f2bu(v.z); s[3] = (short)f2bu(v.w);
    *(short4v*)(mb + i) = s;
    *(short4v*)(yb + i) = s;
}

// ------------------------------ host side ------------------------------------
static void gemmT(hipStream_t st, bool relu, bool obf16,
                  const unsigned short* A, int lda,
                  const unsigned short* B, int ldb,
                  const float* bias, void* C, int ldc, long sC,
                  int M, int N, int K, float alpha, int batch,
                  unsigned short* VTp = nullptr, int vt_col0 = 0,
                  const unsigned short* A2 = nullptr, int a2_col = 0,
                  int kz = 0)
{
    dim3 g(N / 64, M / 128, batch);
    if (obf16) {
        if (relu) gemmT_k<true,  true ><<<g, 256, 0, st>>>(A, A2, a2_col, lda, B, ldb, bias, C, ldc, sC, K, alpha, VTp, vt_col0, kz);
        else      gemmT_k<false, true ><<<g, 256, 0, st>>>(A, A2, a2_col, lda, B, ldb, bias, C, ldc, sC, K, alpha, VTp, vt_col0, kz);
    } else {
        if (relu) gemmT_k<true,  false><<<g, 256, 0, st>>>(A, A2, a2_col, lda, B, ldb, bias, C, ldc, sC, K, alpha, VTp, vt_col0, kz);
        else      gemmT_k<false, false><<<g, 256, 0, st>>>(A, A2, a2_col, lda, B, ldb, bias, C, ldc, sC, K, alpha, VTp, vt_col0, kz);
    }
}

extern "C" void kernel_launch(void* const* d_in, const int* in_sizes, int n_in,
                              void* d_out, int out_size, void* d_ws, size_t ws_size,
                              hipStream_t stream)
{
    const float* x            = (const float*)d_in[0];
    const float* enc_qkv_w    = (const float*)d_in[1];
    const float* enc_qkv_b    = (const float*)d_in[2];
    const float* enc_out_w    = (const float*)d_in[3];
    const float* enc_out_b    = (const float*)d_in[4];
    const float* enc_ff1_w    = (const float*)d_in[5];
    const float* enc_ff1_b    = (const float*)d_in[6];
    const float* enc_ff2_w    = (const float*)d_in[7];
    const float* enc_ff2_b    = (const float*)d_in[8];
    const float* enc_ln1_s    = (const float*)d_in[9];
    const float* enc_ln1_b    = (const float*)d_in[10];
    const float* enc_ln2_s    = (const float*)d_in[11];
    const float* enc_ln2_b    = (const float*)d_in[12];
    const float* dec_sa_qkv_w = (const float*)d_in[13];
    const float* dec_sa_qkv_b = (const float*)d_in[14];
    const float* dec_sa_out_w = (const float*)d_in[15];
    const float* dec_sa_out_b = (const float*)d_in[16];
    const float* dec_ca_qkv_w = (const float*)d_in[17];
    const float* dec_ca_qkv_b = (const float*)d_in[18];
    const float* dec_ca_out_w = (const float*)d_in[19];
    const float* dec_ca_out_b = (const float*)d_in[20];
    const float* dec_ff1_w    = (const float*)d_in[21];
    const float* dec_ff1_b    = (const float*)d_in[22];
    const float* dec_ff2_w    = (const float*)d_in[23];
    const float* dec_ff2_b    = (const float*)d_in[24];
    const float* dec_ln1_s    = (const float*)d_in[25];
    const float* dec_ln1_b    = (const float*)d_in[26];
    const float* dec_ln2_s    = (const float*)d_in[27];
    const float* dec_ln2_b    = (const float*)d_in[28];
    const float* dec_ln3_s    = (const float*)d_in[29];
    const float* dec_ln3_b    = (const float*)d_in[30];
    const float* enc_norm_s   = (const float*)d_in[31];
    const float* enc_norm_b   = (const float*)d_in[32];
    const float* dec_norm_s   = (const float*)d_in[33];
    const float* dec_norm_b   = (const float*)d_in[34];

    char* p = (char*)d_ws;
    auto alloc = [&](size_t bytes) -> char* {
        char* r = p; p += (bytes + 255) & ~(size_t)255; return r;
    };
    float*          MEMf = (float*)alloc(1024 * 512 * 4);
    float*          Yf   = (float*)alloc(1024 * 512 * 4);
    unsigned short* MEMb = (unsigned short*)alloc(1024 * 512 * 2);
    unsigned short* Yb   = (unsigned short*)alloc(1024 * 512 * 2);
    unsigned short* QKVb = (unsigned short*)alloc(1024 * 1536 * 2);
    unsigned short* VT   = (unsigned short*)alloc(8L * 64 * 1024 * 2);
    char*           SLAB = alloc(8L * 1024 * 512 * 2);   // 8 bf16 slabs / 4 fp32 slabs
    unsigned short* F1b  = (unsigned short*)alloc(1024L * 2048 * 2);
    unsigned short* NBb  = (unsigned short*)alloc(1024 * 512 * 2);

    const float* wsrc[10] = {enc_qkv_w, enc_out_w, enc_ff1_w, enc_ff2_w,
                             dec_sa_qkv_w, dec_sa_out_w, dec_ca_qkv_w, dec_ca_out_w,
                             dec_ff1_w, dec_ff2_w};
    const long wper[10] = {1536L*512, 512L*512, 2048L*512, 512L*2048,
                           1536L*512, 512L*512, 1536L*512, 512L*512,
                           2048L*512, 512L*2048};
    long wtot = 0;
    for (int t = 0; t < 10; ++t) wtot += wper[t] * NLAY;

    const size_t used = (size_t)(p - (char*)d_ws);
    const bool preconv = (ws_size > used) && ((ws_size - used) >= (size_t)wtot * 2 + 4096);

    unsigned short* wpre[10] = {};
    unsigned short* slots[2] = {};
    int slot_ctr = 0;
    if (preconv) {
        WCvt wc;
        wc.cum[0] = 0;
        for (int t = 0; t < 10; ++t) {
            wpre[t] = (unsigned short*)alloc((size_t)wper[t] * NLAY * 2);
            wc.src[t] = wsrc[t];
            wc.dst[t] = wpre[t];
            wc.cum[t + 1] = wc.cum[t] + wper[t] * NLAY / 8;
        }
        f2ball_k<<<dim3(2048), 256, 0, stream>>>(wc);
    } else {
        slots[0] = (unsigned short*)alloc(2048L * 512 * 2);
        slots[1] = (unsigned short*)alloc(2048L * 512 * 2);
    }
    auto W = [&](int t, int layer) -> const unsigned short* {
        if (preconv) return wpre[t] + (long)layer * wper[t];
        unsigned short* dst = slots[(slot_ctr++) & 1];
        const long n = wper[t];
        long blocks = (n / 8 + 255) / 256; if (blocks > 2048) blocks = 2048;
        f2b_k<<<dim3((unsigned)blocks), 256, 0, stream>>>(wsrc[t] + (long)layer * wper[t], dst, n);
        return dst;
    };

    float* out_gram = (float*)d_out;
    float* out_attn = out_gram + 1024 * 1024;

    // attention: merged QKV GEMM -> fused attn+proj (bf16 per-head slabs) -> LN<8>
    auto run_attn = [&](const unsigned short* qb, const unsigned short* kvb,
                        int wt_qkv, int wt_o, int layer, const float* bqkv,
                        const float* obias, const float* lns, const float* lnb,
                        float* xf, unsigned short* xb) {
        gemmT(stream, false, true, qb, 512, W(wt_qkv, layer), 512, bqkv,
              QKVb, 1536, 0, 1024, 1536, 512, 1.0f, 1, VT, 1024,
              (qb == kvb) ? nullptr : kvb, 512);
        attnp_k<<<dim3(32, 8), 128, 0, stream>>>(QKVb, VT, W(wt_o, layer),
                                                 (unsigned short*)SLAB);
        ln_k<8, true><<<256, 256, 0, stream>>>(xf, SLAB, obias, lns, lnb, xf, xb);
    };
    // FFN: FF1 (relu, bf16) -> FF2 split-K(4) fp32 slabs -> LN<4>
    auto run_ffn = [&](unsigned short* inb, int wt1, int wt2, int layer,
                       const float* b1, const float* f2bias,
                       const float* lns, const float* lnb,
                       float* xf, unsigned short* xb) {
        gemmT(stream, true, true, inb, 512, W(wt1, layer), 512, b1,
              F1b, 2048, 0, 1024, 2048, 512, 1.0f, 1);
        gemmT(stream, false, false, F1b, 2048, W(wt2, layer), 2048, nullptr,
              SLAB, 512, 524288, 1024, 512, 512, 1.0f, 4, nullptr, 0, nullptr, 0, 512);
        ln_k<4, false><<<256, 256, 0, stream>>>(xf, SLAB, f2bias, lns, lnb, xf, xb);
    };

    init_k<<<512, 256, 0, stream>>>(x, MEMf, Yf, MEMb, Yb);

    // ----------------------------- encoder -----------------------------------
    for (int i = 0; i < NLAY; ++i) {
        run_attn(MEMb, MEMb, 0, 1, i, enc_qkv_b + i * 1536,
                 enc_out_b + i * 512, enc_ln1_s + i * 512, enc_ln1_b + i * 512, MEMf, MEMb);
        run_ffn(MEMb, 2, 3, i, enc_ff1_b + i * 2048, enc_ff2_b + i * 512,
                enc_ln2_s + i * 512, enc_ln2_b + i * 512, MEMf, MEMb);
    }
    ln_k<0, false><<<256, 256, 0, stream>>>(MEMf, nullptr, nullptr, enc_norm_s, enc_norm_b, MEMf, MEMb);

    // ----------------------------- decoder -----------------------------------
    for (int i = 0; i < NLAY; ++i) {
        run_attn(Yb, Yb, 4, 5, i, dec_sa_qkv_b + i * 1536,
                 dec_sa_out_b + i * 512, dec_ln1_s + i * 512, dec_ln1_b + i * 512, Yf, Yb);
        run_attn(Yb, MEMb, 6, 7, i, dec_ca_qkv_b + i * 1536,
                 dec_ca_out_b + i * 512, dec_ln2_s + i * 512, dec_ln2_b + i * 512, Yf, Yb);
        run_ffn(Yb, 8, 9, i, dec_ff1_b + i * 2048, dec_ff2_b + i * 512,
                dec_ln3_s + i * 512, dec_ln3_b + i * 512, Yf, Yb);
    }

    // final: attention_out + n = rownorm (fused), gram = n@n^T
    lnl2_k<<<256, 256, 0, stream>>>(Yf, dec_norm_s, dec_norm_b, out_attn, NBb);
    gemm3_k<<<dim3(16, 16), 256, 0, stream>>>(NBb, 512, NBb, 512, out_gram, 1024, 512);
}

// Round 13
// 1154.624 us; speedup vs baseline: 1.0778x; 1.0778x over previous
//
#include <hip/hip_runtime.h>

// MyTransformer: 6-enc + 6-dec, S=1024, D=512, H=8x64, FF=2048.
// Round 12: exact round-10 structure (64x64-tile gemm3, 48KB, 3 blocks/CU;
// fused attn+proj; split-K FF2 + LN merge) with ONE isolated change:
// attn proj slabs in bf16 (halves slab write+read traffic). FF2 slabs fp32.

#define NLAY 6

typedef __attribute__((ext_vector_type(8))) short short8;
typedef __attribute__((ext_vector_type(4))) short short4v;
typedef __attribute__((ext_vector_type(4))) float f32x4;

typedef __attribute__((address_space(3))) short lds_short;
typedef __attribute__((address_space(1))) const unsigned short g_ushort;

__device__ __forceinline__ void gload16(const unsigned short* g, short* l) {
    __builtin_amdgcn_global_load_lds((g_ushort*)g, (lds_short*)l, 16, 0, 0);
}

__device__ __forceinline__ void waitvm(int n) {   // wave-uniform literal waits
    if (n == 0)      asm volatile("s_waitcnt vmcnt(0)" ::: "memory");
    else if (n == 4) asm volatile("s_waitcnt vmcnt(4)" ::: "memory");
    else             asm volatile("s_waitcnt vmcnt(8)" ::: "memory");
}

__device__ inline unsigned short f2bu(float x) {
    unsigned u = __builtin_bit_cast(unsigned, x);
    unsigned r = (u + 0x7fffu + ((u >> 16) & 1u)) >> 16;   // RNE
    return (unsigned short)r;
}

__device__ inline float b2f(unsigned short u) {
    return __builtin_bit_cast(float, (unsigned)u << 16);
}

// ------------- fp32 -> bf16 weight cvt: flat balanced grid, 1 dispatch -------
struct WCvt {
    const float* src[10];
    unsigned short* dst[10];
    long cum[11];           // prefix sums in 8-element chunks
};

__global__ __launch_bounds__(256)
void f2ball_k(WCvt wc)
{
    const long total = wc.cum[10];
    for (long c = (long)blockIdx.x * 256 + threadIdx.x; c < total;
         c += (long)gridDim.x * 256) {
        int t = 0;
        #pragma unroll
        for (int i = 1; i < 10; ++i) if (c >= wc.cum[i]) t = i;
        const long o = (c - wc.cum[t]) * 8;
        const float* s = wc.src[t];
        unsigned short* d = wc.dst[t];
        const float4 a = *(const float4*)(s + o);
        const float4 b = *(const float4*)(s + o + 4);
        short8 v;
        v[0] = (short)f2bu(a.x); v[1] = (short)f2bu(a.y);
        v[2] = (short)f2bu(a.z); v[3] = (short)f2bu(a.w);
        v[4] = (short)f2bu(b.x); v[5] = (short)f2bu(b.y);
        v[6] = (short)f2bu(b.z); v[7] = (short)f2bu(b.w);
        *(short8*)(d + o) = v;
    }
}

__global__ __launch_bounds__(256)
void f2b_k(const float* __restrict__ s, unsigned short* __restrict__ d, long n)
{
    const long stride = (long)gridDim.x * 256;
    for (long i = (long)blockIdx.x * 256 + threadIdx.x; i * 8 < n; i += stride) {
        const long o = i * 8;
        const float4 a = *(const float4*)(s + o);
        const float4 b = *(const float4*)(s + o + 4);
        short8 v;
        v[0] = (short)f2bu(a.x); v[1] = (short)f2bu(a.y);
        v[2] = (short)f2bu(a.z); v[3] = (short)f2bu(a.w);
        v[4] = (short)f2bu(b.x); v[5] = (short)f2bu(b.y);
        v[6] = (short)f2bu(b.z); v[7] = (short)f2bu(b.w);
        *(short8*)(d + o) = v;
    }
}

// ---------------- 4-wave MFMA GEMM: C = alpha * A @ B^T + bias ---------------
// 64x64 tile, BK=64, 3-buffer gload_lds pipeline (48 KB LDS -> 3 blocks/CU).
// Split-K via kz (element offset per z), slab out via sC. A2: merged QKV.
// VTp: V-transpose scatter for cols >= vt_col0.
template<bool RELU, bool OBF16>
__global__ __launch_bounds__(256)
void gemm3_k(const unsigned short* __restrict__ A,
             const unsigned short* __restrict__ A2, int a2_col, int lda,
             const unsigned short* __restrict__ B, int ldb,
             const float* __restrict__ bias,
             void* __restrict__ Cv, int ldc, long sC,
             int K, float alpha,
             unsigned short* __restrict__ VTp, int vt_col0, int kz)
{
    __shared__ __align__(16) short As[3][4096];
    __shared__ __align__(16) short Bs[3][4096];
    const int bz = blockIdx.z;
    const int m0 = blockIdx.y * 64;
    const int n0 = blockIdx.x * 64;
    if (A2 && n0 >= a2_col) A = A2;
    A += (long)bz * kz;
    B += (long)bz * kz;
    const int tid = threadIdx.x;
    const int w  = tid >> 6;
    const int l  = tid & 63;
    const int fr = l & 15;
    const int kc = l >> 4;

    f32x4 acc[4] = {};
    const int T = K >> 6;

    auto FILL = [&](int t, int buf) {
        const int k0 = t * 64;
        #pragma unroll
        for (int it = 0; it < 2; ++it) {
            const int row = w * 16 + it * 8 + (l >> 3);
            const int sl  = ((l & 7) ^ (row & 7)) * 8;
            gload16(A + (long)(m0 + row) * lda + k0 + sl, &As[buf][(w * 16 + it * 8) * 64]);
            gload16(B + (long)(n0 + row) * ldb + k0 + sl, &Bs[buf][(w * 16 + it * 8) * 64]);
        }
    };

    FILL(0, 0);
    if (T > 1) FILL(1, 1);
    for (int t = 0; t < T; ++t) {
        waitvm(t + 1 < T ? 4 : 0);
        __builtin_amdgcn_sched_barrier(0);
        __builtin_amdgcn_s_barrier();
        if (t + 2 < T) FILL(t + 2, (t + 2) % 3);
        const int cb = t % 3;
        #pragma unroll
        for (int ks = 0; ks < 2; ++ks) {
            const int arow = w * 16 + fr;
            const short8 af = *(const short8*)&As[cb][arow * 64 + (((ks * 4 + kc) ^ (arow & 7)) * 8)];
            #pragma unroll
            for (int c = 0; c < 4; ++c) {
                const int brow = c * 16 + fr;
                const short8 bf = *(const short8*)&Bs[cb][brow * 64 + (((ks * 4 + kc) ^ (brow & 7)) * 8)];
                acc[c] = __builtin_amdgcn_mfma_f32_16x16x32_bf16(af, bf, acc[c], 0, 0, 0);
            }
        }
    }

    #pragma unroll
    for (int c = 0; c < 4; ++c) {
        const int n = n0 + c * 16 + fr;
        const float bv = bias ? bias[n] : 0.0f;
        const bool do_vt = (VTp != nullptr) && (n >= vt_col0);
        #pragma unroll
        for (int i = 0; i < 4; ++i) {
            const long m = m0 + w * 16 + kc * 4 + i;
            float v = acc[c][i] * alpha + bv;
            if (RELU) v = fmaxf(v, 0.0f);
            if (OBF16) ((unsigned short*)Cv)[bz * sC + m * ldc + n] = f2bu(v);
            else       ((float*)Cv)[bz * sC + m * ldc + n] = v;
            if (do_vt) {
                const int vc = n - vt_col0;
                VTp[(long)(vc >> 6) * 65536 + (long)(vc & 63) * 1024 + m] = f2bu(v);
            }
        }
    }
}

// ------- fused attention + out-projection -> per-head bf16 slabs -------------
// Grid (32 q-tiles of 32 rows, 8 heads), 128 thr = 2 waves. 2-buf K/V (36 KB).
__global__ __launch_bounds__(128)
void attnp_k(const unsigned short* __restrict__ QKVb,   // [1024][1536]
             const unsigned short* __restrict__ VT,     // [8][64][1024]
             const unsigned short* __restrict__ wo,     // [512][512] bf16
             unsigned short* __restrict__ SLABb)        // 8 x [1024][512] bf16
{
    __shared__ __align__(16) short U[18432];   // 36 KB
    short* Ks = U;            // 2 x 4096
    short* Vs = U + 8192;     // 2 x 4096
    short* Ps = U + 16384;    // 2 x 1024
    const int qt = blockIdx.x;
    const int h  = blockIdx.y;
    const int tid = threadIdx.x;
    const int w  = tid >> 6;
    const int l  = tid & 63;
    const int fr = l & 15;
    const int kc = l >> 4;

    const int qrow = qt * 32 + w * 16 + fr;
    short8 qf[2];
    qf[0] = *(const short8*)(QKVb + (long)qrow * 1536 + h * 64 + kc * 8);
    qf[1] = *(const short8*)(QKVb + (long)qrow * 1536 + h * 64 + 32 + kc * 8);

    auto FILL = [&](int t, int buf) {
        const int kb = t * 64;
        #pragma unroll
        for (int it = 0; it < 4; ++it) {
            const int row = it * 16 + w * 8 + (l >> 3);
            const int sl  = ((l & 7) ^ (row & 7)) * 8;
            gload16(QKVb + (long)(kb + row) * 1536 + 512 + h * 64 + sl,
                    Ks + buf * 4096 + (it * 16 + w * 8) * 64);
            gload16(VT + (long)h * 65536 + (long)row * 1024 + kb + sl,
                    Vs + buf * 4096 + (it * 16 + w * 8) * 64);
        }
    };

    float m_i[4], l_i[4];
    f32x4 acc_o[4] = {};
    #pragma unroll
    for (int i = 0; i < 4; ++i) { m_i[i] = -1e30f; l_i[i] = 0.f; }

    short* ps = Ps + w * 1024;

    FILL(0, 0); FILL(1, 1);
    for (int t = 0; t < 16; ++t) {
        waitvm(t == 15 ? 0 : 8);
        __builtin_amdgcn_sched_barrier(0);
        __builtin_amdgcn_s_barrier();

        f32x4 sacc[4] = {};
        const int cb = t & 1;
        #pragma unroll
        for (int ks = 0; ks < 2; ++ks) {
            #pragma unroll
            for (int c = 0; c < 4; ++c) {
                const int krow = c * 16 + fr;
                const short8 kf = *(const short8*)(Ks + cb * 4096 + krow * 64 + (((ks * 4 + kc) ^ (krow & 7)) * 8));
                sacc[c] = __builtin_amdgcn_mfma_f32_16x16x32_bf16(qf[ks], kf, sacc[c], 0, 0, 0);
            }
        }

        float p[4][4];
        #pragma unroll
        for (int i = 0; i < 4; ++i) {
            float tm = fmaxf(fmaxf(sacc[0][i], sacc[1][i]), fmaxf(sacc[2][i], sacc[3][i]));
            #pragma unroll
            for (int off = 8; off; off >>= 1) tm = fmaxf(tm, __shfl_xor(tm, off));
            tm *= 0.125f;
            const float mn = fmaxf(m_i[i], tm);
            const float sc = __expf(m_i[i] - mn);
            m_i[i] = mn;
            float ts = 0.f;
            #pragma unroll
            for (int c = 0; c < 4; ++c) { p[c][i] = __expf(sacc[c][i] * 0.125f - mn); ts += p[c][i]; }
            #pragma unroll
            for (int off = 8; off; off >>= 1) ts += __shfl_xor(ts, off);
            l_i[i] = l_i[i] * sc + ts;
            #pragma unroll
            for (int c = 0; c < 4; ++c) acc_o[c][i] *= sc;
        }

        #pragma unroll
        for (int c = 0; c < 4; ++c) {
            const int col = c * 16 + fr;
            #pragma unroll
            for (int i = 0; i < 4; ++i) {
                const int row = kc * 4 + i;
                ps[row * 64 + (((col >> 3) ^ (row & 7)) * 8) + (col & 7)] = (short)f2bu(p[c][i]);
            }
        }
        short8 pf[2];
        pf[0] = *(const short8*)(ps + fr * 64 + ((kc ^ (fr & 7)) * 8));
        pf[1] = *(const short8*)(ps + fr * 64 + (((4 + kc) ^ (fr & 7)) * 8));

        #pragma unroll
        for (int ks = 0; ks < 2; ++ks) {
            #pragma unroll
            for (int c = 0; c < 4; ++c) {
                const int drow = c * 16 + fr;
                const short8 vf = *(const short8*)(Vs + cb * 4096 + drow * 64 + (((ks * 4 + kc) ^ (drow & 7)) * 8));
                acc_o[c] = __builtin_amdgcn_mfma_f32_16x16x32_bf16(pf[ks], vf, acc_o[c], 0, 0, 0);
            }
        }
        __builtin_amdgcn_s_barrier();
        if (t + 2 < 16) FILL(t + 2, (t + 2) & 1);
    }

    // -------- epilogue: O (regs) @ Wo_h^T -> per-head bf16 slab --------
    short* po = Ps + w * 1024;   // reuse P region: O as A-frag layout
    #pragma unroll
    for (int c = 0; c < 4; ++c) {
        const int col = c * 16 + fr;
        #pragma unroll
        for (int i = 0; i < 4; ++i) {
            const int r = kc * 4 + i;
            po[r * 64 + (((col >> 3) ^ (r & 7)) * 8) + (col & 7)] =
                (short)f2bu(acc_o[c][i] / l_i[i]);
        }
    }
    __syncthreads();   // retire K/V reads; po visible

    short* Wos = U;    // reuse Ks region: 2 x 4096 (64x64 bf16 chunks)
    unsigned short* SLABh = SLABb + (long)h * 524288;
    const int orow = qt * 32 + w * 16;

    auto WSTAGE = [&](int c8, int buf) {
        const int n0c = c8 * 64;
        #pragma unroll
        for (int it = 0; it < 4; ++it) {
            const int rb  = w * 32 + it * 8;
            const int row = rb + (l >> 3);
            const int sl  = ((l & 7) ^ (row & 7)) * 8;
            gload16(wo + (long)(n0c + row) * 512 + h * 64 + sl, Wos + buf * 4096 + rb * 64);
        }
    };

    WSTAGE(0, 0);
    for (int c8 = 0; c8 < 8; ++c8) {
        if (c8) __syncthreads();
        if (c8 + 1 < 8) WSTAGE(c8 + 1, (c8 + 1) & 1);
        waitvm(c8 + 1 < 8 ? 4 : 0);
        __builtin_amdgcn_sched_barrier(0);
        __builtin_amdgcn_s_barrier();
        const int buf = c8 & 1;
        f32x4 a2[4] = {};
        #pragma unroll
        for (int ks = 0; ks < 2; ++ks) {
            const int q = ks * 4 + kc;
            const short8 af = *(const short8*)(po + fr * 64 + ((q ^ (fr & 7)) * 8));
            #pragma unroll
            for (int ct = 0; ct < 4; ++ct) {
                const int brn = ct * 16 + fr;
                const short8 bf = *(const short8*)(Wos + buf * 4096 + brn * 64 + ((q ^ (brn & 7)) * 8));
                a2[ct] = __builtin_amdgcn_mfma_f32_16x16x32_bf16(af, bf, a2[ct], 0, 0, 0);
            }
        }
        #pragma unroll
        for (int ct = 0; ct < 4; ++ct) {
            const int n = c8 * 64 + ct * 16 + fr;
            #pragma unroll
            for (int i = 0; i < 4; ++i)
                SLABh[(long)(orow + kc * 4 + i) * 512 + n] = f2bu(a2[ct][i]);
        }
    }
}

// ---- LayerNorm-as-merge: out = LN(x + sum_slabs + bias)*s + b ---------------
// SB16: slabs are bf16 (attn proj partials); else fp32 (FF2 split-K).
template<int NSLAB, bool SB16>
__global__ __launch_bounds__(256)
void ln_k(const float* __restrict__ x, const void* __restrict__ slab,
          const float* __restrict__ bias,
          const float* __restrict__ s, const float* __restrict__ b,
          float* __restrict__ out, unsigned short* __restrict__ outb)
{
    const int lane = threadIdx.x & 63;
    const int row  = (blockIdx.x << 2) + (threadIdx.x >> 6);
    const float* px = x + (long)row * 512;
    float v[8];
    float sum = 0.f;
    #pragma unroll
    for (int i = 0; i < 8; ++i) {
        const int j = lane + (i << 6);
        v[i] = px[j];
        #pragma unroll
        for (int t = 0; t < NSLAB; ++t) {
            if (SB16) v[i] += b2f(((const unsigned short*)slab)[(long)t * 524288 + (long)row * 512 + j]);
            else      v[i] += ((const float*)slab)[(long)t * 524288 + (long)row * 512 + j];
        }
        if (NSLAB > 0) v[i] += bias[j];
        sum += v[i];
    }
    #pragma unroll
    for (int off = 32; off; off >>= 1) sum += __shfl_xor(sum, off);
    const float m = sum * (1.0f / 512.0f);
    float s2 = 0.f;
    #pragma unroll
    for (int i = 0; i < 8; ++i) { const float d = v[i] - m; s2 += d * d; }
    #pragma unroll
    for (int off = 32; off; off >>= 1) s2 += __shfl_xor(s2, off);
    const float inv = rsqrtf(s2 * (1.0f / 512.0f) + 1e-5f);
    #pragma unroll
    for (int i = 0; i < 8; ++i) {
        const int j = lane + (i << 6);
        const float r = (v[i] - m) * inv * s[j] + b[j];
        out[(long)row * 512 + j] = r;
        if (outb) outb[(long)row * 512 + j] = f2bu(r);
    }
}

// -------- fused final LN + L2-normalize --------------------------------------
__global__ __launch_bounds__(256)
void lnl2_k(const float* __restrict__ x,
            const float* __restrict__ s, const float* __restrict__ b,
            float* __restrict__ out_attn, unsigned short* __restrict__ nb)
{
    const int lane = threadIdx.x & 63;
    const int row  = (blockIdx.x << 2) + (threadIdx.x >> 6);
    const float* px = x + (long)row * 512;
    float v[8];
    float sum = 0.f;
    #pragma unroll
    for (int i = 0; i < 8; ++i) { v[i] = px[lane + (i << 6)]; sum += v[i]; }
    #pragma unroll
    for (int off = 32; off; off >>= 1) sum += __shfl_xor(sum, off);
    const float m = sum * (1.0f / 512.0f);
    float s2 = 0.f;
    #pragma unroll
    for (int i = 0; i < 8; ++i) { const float d = v[i] - m; s2 += d * d; }
    #pragma unroll
    for (int off = 32; off; off >>= 1) s2 += __shfl_xor(s2, off);
    const float inv = rsqrtf(s2 * (1.0f / 512.0f) + 1e-5f);
    float nrm = 0.f;
    #pragma unroll
    for (int i = 0; i < 8; ++i) {
        const int j = lane + (i << 6);
        v[i] = (v[i] - m) * inv * s[j] + b[j];
        out_attn[(long)row * 512 + j] = v[i];
        nrm += v[i] * v[i];
    }
    #pragma unroll
    for (int off = 32; off; off >>= 1) nrm += __shfl_xor(nrm, off);
    const float rinv = rsqrtf(nrm);
    #pragma unroll
    for (int i = 0; i < 8; ++i)
        nb[(long)row * 512 + lane + (i << 6)] = f2bu(v[i] * rinv);
}

// -------- init: x -> MEMf, Yf (fp32) + MEMb, Yb (bf16) -----------------------
__global__ __launch_bounds__(256)
void init_k(const float* __restrict__ x, float* __restrict__ mf, float* __restrict__ yf,
            unsigned short* __restrict__ mb, unsigned short* __restrict__ yb)
{
    const long i = ((long)blockIdx.x * 256 + threadIdx.x) * 4;
    const float4 v = *(const float4*)(x + i);
    *(float4*)(mf + i) = v;
    *(float4*)(yf + i) = v;
    short4v s;
    s[0] = (short)f2bu(v.x); s[1] = (short)f2bu(v.y);
    s[2] = (short)f2bu(v.z); s[3] = (short)f2bu(v.w);
    *(short4v*)(mb + i) = s;
    *(short4v*)(yb + i) = s;
}

// ------------------------------ host side ------------------------------------
static void gemm3(hipStream_t st, bool relu, bool obf16,
                  const unsigned short* A, int lda,
                  const unsigned short* B, int ldb,
                  const float* bias, void* C, int ldc, long sC,
                  int M, int N, int K, float alpha, int batch,
                  unsigned short* VTp = nullptr, int vt_col0 = 0,
                  const unsigned short* A2 = nullptr, int a2_col = 0,
                  int kz = 0)
{
    dim3 g(N / 64, M / 64, batch);
    if (obf16) {
        if (relu) gemm3_k<true,  true ><<<g, 256, 0, st>>>(A, A2, a2_col, lda, B, ldb, bias, C, ldc, sC, K, alpha, VTp, vt_col0, kz);
        else      gemm3_k<false, true ><<<g, 256, 0, st>>>(A, A2, a2_col, lda, B, ldb, bias, C, ldc, sC, K, alpha, VTp, vt_col0, kz);
    } else {
        if (relu) gemm3_k<true,  false><<<g, 256, 0, st>>>(A, A2, a2_col, lda, B, ldb, bias, C, ldc, sC, K, alpha, VTp, vt_col0, kz);
        else      gemm3_k<false, false><<<g, 256, 0, st>>>(A, A2, a2_col, lda, B, ldb, bias, C, ldc, sC, K, alpha, VTp, vt_col0, kz);
    }
}

extern "C" void kernel_launch(void* const* d_in, const int* in_sizes, int n_in,
                              void* d_out, int out_size, void* d_ws, size_t ws_size,
                              hipStream_t stream)
{
    const float* x            = (const float*)d_in[0];
    const float* enc_qkv_w    = (const float*)d_in[1];
    const float* enc_qkv_b    = (const float*)d_in[2];
    const float* enc_out_w    = (const float*)d_in[3];
    const float* enc_out_b    = (const float*)d_in[4];
    const float* enc_ff1_w    = (const float*)d_in[5];
    const float* enc_ff1_b    = (const float*)d_in[6];
    const float* enc_ff2_w    = (const float*)d_in[7];
    const float* enc_ff2_b    = (const float*)d_in[8];
    const float* enc_ln1_s    = (const float*)d_in[9];
    const float* enc_ln1_b    = (const float*)d_in[10];
    const float* enc_ln2_s    = (const float*)d_in[11];
    const float* enc_ln2_b    = (const float*)d_in[12];
    const float* dec_sa_qkv_w = (const float*)d_in[13];
    const float* dec_sa_qkv_b = (const float*)d_in[14];
    const float* dec_sa_out_w = (const float*)d_in[15];
    const float* dec_sa_out_b = (const float*)d_in[16];
    const float* dec_ca_qkv_w = (const float*)d_in[17];
    const float* dec_ca_qkv_b = (const float*)d_in[18];
    const float* dec_ca_out_w = (const float*)d_in[19];
    const float* dec_ca_out_b = (const float*)d_in[20];
    const float* dec_ff1_w    = (const float*)d_in[21];
    const float* dec_ff1_b    = (const float*)d_in[22];
    const float* dec_ff2_w    = (const float*)d_in[23];
    const float* dec_ff2_b    = (const float*)d_in[24];
    const float* dec_ln1_s    = (const float*)d_in[25];
    const float* dec_ln1_b    = (const float*)d_in[26];
    const float* dec_ln2_s    = (const float*)d_in[27];
    const float* dec_ln2_b    = (const float*)d_in[28];
    const float* dec_ln3_s    = (const float*)d_in[29];
    const float* dec_ln3_b    = (const float*)d_in[30];
    const float* enc_norm_s   = (const float*)d_in[31];
    const float* enc_norm_b   = (const float*)d_in[32];
    const float* dec_norm_s   = (const float*)d_in[33];
    const float* dec_norm_b   = (const float*)d_in[34];

    char* p = (char*)d_ws;
    auto alloc = [&](size_t bytes) -> char* {
        char* r = p; p += (bytes + 255) & ~(size_t)255; return r;
    };
    float*          MEMf = (float*)alloc(1024 * 512 * 4);
    float*          Yf   = (float*)alloc(1024 * 512 * 4);
    unsigned short* MEMb = (unsigned short*)alloc(1024 * 512 * 2);
    unsigned short* Yb   = (unsigned short*)alloc(1024 * 512 * 2);
    unsigned short* QKVb = (unsigned short*)alloc(1024 * 1536 * 2);
    unsigned short* VT   = (unsigned short*)alloc(8L * 64 * 1024 * 2);
    char*           SLAB = alloc(8L * 1024 * 512 * 2);   // 8 bf16 / 4 fp32 slabs
    unsigned short* F1b  = (unsigned short*)alloc(1024L * 2048 * 2);
    unsigned short* NBb  = (unsigned short*)alloc(1024 * 512 * 2);

    const float* wsrc[10] = {enc_qkv_w, enc_out_w, enc_ff1_w, enc_ff2_w,
                             dec_sa_qkv_w, dec_sa_out_w, dec_ca_qkv_w, dec_ca_out_w,
                             dec_ff1_w, dec_ff2_w};
    const long wper[10] = {1536L*512, 512L*512, 2048L*512, 512L*2048,
                           1536L*512, 512L*512, 1536L*512, 512L*512,
                           2048L*512, 512L*2048};
    long wtot = 0;
    for (int t = 0; t < 10; ++t) wtot += wper[t] * NLAY;

    const size_t used = (size_t)(p - (char*)d_ws);
    const bool preconv = (ws_size > used) && ((ws_size - used) >= (size_t)wtot * 2 + 4096);

    unsigned short* wpre[10] = {};
    unsigned short* slots[2] = {};
    int slot_ctr = 0;
    if (preconv) {
        WCvt wc;
        wc.cum[0] = 0;
        for (int t = 0; t < 10; ++t) {
            wpre[t] = (unsigned short*)alloc((size_t)wper[t] * NLAY * 2);
            wc.src[t] = wsrc[t];
            wc.dst[t] = wpre[t];
            wc.cum[t + 1] = wc.cum[t] + wper[t] * NLAY / 8;
        }
        f2ball_k<<<dim3(2048), 256, 0, stream>>>(wc);
    } else {
        slots[0] = (unsigned short*)alloc(2048L * 512 * 2);
        slots[1] = (unsigned short*)alloc(2048L * 512 * 2);
    }
    auto W = [&](int t, int layer) -> const unsigned short* {
        if (preconv) return wpre[t] + (long)layer * wper[t];
        unsigned short* dst = slots[(slot_ctr++) & 1];
        const long n = wper[t];
        long blocks = (n / 8 + 255) / 256; if (blocks > 2048) blocks = 2048;
        f2b_k<<<dim3((unsigned)blocks), 256, 0, stream>>>(wsrc[t] + (long)layer * wper[t], dst, n);
        return dst;
    };

    float* out_gram = (float*)d_out;
    float* out_attn = out_gram + 1024 * 1024;

    // attention: merged QKV GEMM -> fused attn+proj (bf16 per-head slabs) -> LN<8>
    auto run_attn = [&](const unsigned short* qb, const unsigned short* kvb,
                        int wt_qkv, int wt_o, int layer, const float* bqkv,
                        const float* obias, const float* lns, const float* lnb,
                        float* xf, unsigned short* xb) {
        gemm3(stream, false, true, qb, 512, W(wt_qkv, layer), 512, bqkv,
              QKVb, 1536, 0, 1024, 1536, 512, 1.0f, 1, VT, 1024,
              (qb == kvb) ? nullptr : kvb, 512);
        attnp_k<<<dim3(32, 8), 128, 0, stream>>>(QKVb, VT, W(wt_o, layer),
                                                 (unsigned short*)SLAB);
        ln_k<8, true><<<256, 256, 0, stream>>>(xf, SLAB, obias, lns, lnb, xf, xb);
    };
    // FFN: FF1 (relu, bf16) -> FF2 split-K(4) fp32 slabs -> LN<4>
    auto run_ffn = [&](unsigned short* inb, int wt1, int wt2, int layer,
                       const float* b1, const float* f2bias,
                       const float* lns, const float* lnb,
                       float* xf, unsigned short* xb) {
        gemm3(stream, true, true, inb, 512, W(wt1, layer), 512, b1,
              F1b, 2048, 0, 1024, 2048, 512, 1.0f, 1);
        gemm3(stream, false, false, F1b, 2048, W(wt2, layer), 2048, nullptr,
              SLAB, 512, 524288, 1024, 512, 512, 1.0f, 4, nullptr, 0, nullptr, 0, 512);
        ln_k<4, false><<<256, 256, 0, stream>>>(xf, SLAB, f2bias, lns, lnb, xf, xb);
    };

    init_k<<<512, 256, 0, stream>>>(x, MEMf, Yf, MEMb, Yb);

    // ----------------------------- encoder -----------------------------------
    for (int i = 0; i < NLAY; ++i) {
        run_attn(MEMb, MEMb, 0, 1, i, enc_qkv_b + i * 1536,
                 enc_out_b + i * 512, enc_ln1_s + i * 512, enc_ln1_b + i * 512, MEMf, MEMb);
        run_ffn(MEMb, 2, 3, i, enc_ff1_b + i * 2048, enc_ff2_b + i * 512,
                enc_ln2_s + i * 512, enc_ln2_b + i * 512, MEMf, MEMb);
    }
    ln_k<0, false><<<256, 256, 0, stream>>>(MEMf, nullptr, nullptr, enc_norm_s, enc_norm_b, MEMf, MEMb);

    // ----------------------------- decoder -----------------------------------
    for (int i = 0; i < NLAY; ++i) {
        run_attn(Yb, Yb, 4, 5, i, dec_sa_qkv_b + i * 1536,
                 dec_sa_out_b + i * 512, dec_ln1_s + i * 512, dec_ln1_b + i * 512, Yf, Yb);
        run_attn(Yb, MEMb, 6, 7, i, dec_ca_qkv_b + i * 1536,
                 dec_ca_out_b + i * 512, dec_ln2_s + i * 512, dec_ln2_b + i * 512, Yf, Yb);
        run_ffn(Yb, 8, 9, i, dec_ff1_b + i * 2048, dec_ff2_b + i * 512,
                dec_ln3_s + i * 512, dec_ln3_b + i * 512, Yf, Yb);
    }

    // final: attention_out + n = rownorm (fused), gram = n@n^T
    lnl2_k<<<256, 256, 0, stream>>>(Yf, dec_norm_s, dec_norm_b, out_attn, NBb);
    gemm3(stream, false, false, NBb, 512, NBb, 512, nullptr,
          out_gram, 1024, 0, 1024, 1024, 512, 1.0f, 1);
}

// Round 14
// 1029.350 us; speedup vs baseline: 1.2090x; 1.1217x over previous
//
#include <hip/hip_runtime.h>

// MyTransformer: 6-enc + 6-dec, S=1024, D=512, H=8x64, FF=2048.
// Round 13: attnp K-split (16-row blocks, 512 blocks, 2 waves on disjoint
// K-halves, barrier-free main loop, exact flash merge); decoder cross-attn
// K/V hoisted into one batched z-strided GEMM. Rest = round-12 structure.

#define NLAY 6

typedef __attribute__((ext_vector_type(8))) short short8;
typedef __attribute__((ext_vector_type(4))) short short4v;
typedef __attribute__((ext_vector_type(4))) float f32x4;

typedef __attribute__((address_space(3))) short lds_short;
typedef __attribute__((address_space(1))) const unsigned short g_ushort;

__device__ __forceinline__ void gload16(const unsigned short* g, short* l) {
    __builtin_amdgcn_global_load_lds((g_ushort*)g, (lds_short*)l, 16, 0, 0);
}

__device__ __forceinline__ void waitvm(int n) {   // wave-uniform literal waits
    if (n == 0)       asm volatile("s_waitcnt vmcnt(0)" ::: "memory");
    else if (n == 4)  asm volatile("s_waitcnt vmcnt(4)" ::: "memory");
    else if (n == 8)  asm volatile("s_waitcnt vmcnt(8)" ::: "memory");
    else              asm volatile("s_waitcnt vmcnt(16)" ::: "memory");
}

__device__ inline unsigned short f2bu(float x) {
    unsigned u = __builtin_bit_cast(unsigned, x);
    unsigned r = (u + 0x7fffu + ((u >> 16) & 1u)) >> 16;   // RNE
    return (unsigned short)r;
}

__device__ inline float b2f(unsigned short u) {
    return __builtin_bit_cast(float, (unsigned)u << 16);
}

// ------------- fp32 -> bf16 weight cvt: flat balanced grid, 1 dispatch -------
struct WCvt {
    const float* src[10];
    unsigned short* dst[10];
    long cum[11];           // prefix sums in 8-element chunks
};

__global__ __launch_bounds__(256)
void f2ball_k(WCvt wc)
{
    const long total = wc.cum[10];
    for (long c = (long)blockIdx.x * 256 + threadIdx.x; c < total;
         c += (long)gridDim.x * 256) {
        int t = 0;
        #pragma unroll
        for (int i = 1; i < 10; ++i) if (c >= wc.cum[i]) t = i;
        const long o = (c - wc.cum[t]) * 8;
        const float* s = wc.src[t];
        unsigned short* d = wc.dst[t];
        const float4 a = *(const float4*)(s + o);
        const float4 b = *(const float4*)(s + o + 4);
        short8 v;
        v[0] = (short)f2bu(a.x); v[1] = (short)f2bu(a.y);
        v[2] = (short)f2bu(a.z); v[3] = (short)f2bu(a.w);
        v[4] = (short)f2bu(b.x); v[5] = (short)f2bu(b.y);
        v[6] = (short)f2bu(b.z); v[7] = (short)f2bu(b.w);
        *(short8*)(d + o) = v;
    }
}

__global__ __launch_bounds__(256)
void f2b_k(const float* __restrict__ s, unsigned short* __restrict__ d, long n)
{
    const long stride = (long)gridDim.x * 256;
    for (long i = (long)blockIdx.x * 256 + threadIdx.x; i * 8 < n; i += stride) {
        const long o = i * 8;
        const float4 a = *(const float4*)(s + o);
        const float4 b = *(const float4*)(s + o + 4);
        short8 v;
        v[0] = (short)f2bu(a.x); v[1] = (short)f2bu(a.y);
        v[2] = (short)f2bu(a.z); v[3] = (short)f2bu(a.w);
        v[4] = (short)f2bu(b.x); v[5] = (short)f2bu(b.y);
        v[6] = (short)f2bu(b.z); v[7] = (short)f2bu(b.w);
        *(short8*)(d + o) = v;
    }
}

// ---------------- 4-wave MFMA GEMM: C = alpha * A @ B^T + bias ---------------
// 64x64 tile, BK=64, 3-buffer gload_lds pipeline (48 KB -> 3 blocks/CU).
// Per-z: A/B += z*kz (split-K); B += z*zB, bias += z*zBias, VT += z*zVT,
// C += z*sC (batched). A2: merged-input column split. VTp: V scatter.
template<bool RELU, bool OBF16>
__global__ __launch_bounds__(256)
void gemm3_k(const unsigned short* __restrict__ A,
             const unsigned short* __restrict__ A2, int a2_col, int lda,
             const unsigned short* __restrict__ B, int ldb,
             const float* __restrict__ bias,
             void* __restrict__ Cv, int ldc, long sC,
             int K, float alpha,
             unsigned short* __restrict__ VTp, int vt_col0, int kz,
             long zB, int zBias, long zVT)
{
    __shared__ __align__(16) short As[3][4096];
    __shared__ __align__(16) short Bs[3][4096];
    const int bz = blockIdx.z;
    const int m0 = blockIdx.y * 64;
    const int n0 = blockIdx.x * 64;
    if (A2 && n0 >= a2_col) A = A2;
    A += (long)bz * kz;
    B += (long)bz * kz + (long)bz * zB;
    if (bias) bias += (long)bz * zBias;
    if (VTp)  VTp  += (long)bz * zVT;
    const int tid = threadIdx.x;
    const int w  = tid >> 6;
    const int l  = tid & 63;
    const int fr = l & 15;
    const int kc = l >> 4;

    f32x4 acc[4] = {};
    const int T = K >> 6;

    auto FILL = [&](int t, int buf) {
        const int k0 = t * 64;
        #pragma unroll
        for (int it = 0; it < 2; ++it) {
            const int row = w * 16 + it * 8 + (l >> 3);
            const int sl  = ((l & 7) ^ (row & 7)) * 8;
            gload16(A + (long)(m0 + row) * lda + k0 + sl, &As[buf][(w * 16 + it * 8) * 64]);
            gload16(B + (long)(n0 + row) * ldb + k0 + sl, &Bs[buf][(w * 16 + it * 8) * 64]);
        }
    };

    FILL(0, 0);
    if (T > 1) FILL(1, 1);
    for (int t = 0; t < T; ++t) {
        waitvm(t + 1 < T ? 4 : 0);
        __builtin_amdgcn_sched_barrier(0);
        __builtin_amdgcn_s_barrier();
        if (t + 2 < T) FILL(t + 2, (t + 2) % 3);
        const int cb = t % 3;
        #pragma unroll
        for (int ks = 0; ks < 2; ++ks) {
            const int arow = w * 16 + fr;
            const short8 af = *(const short8*)&As[cb][arow * 64 + (((ks * 4 + kc) ^ (arow & 7)) * 8)];
            #pragma unroll
            for (int c = 0; c < 4; ++c) {
                const int brow = c * 16 + fr;
                const short8 bf = *(const short8*)&Bs[cb][brow * 64 + (((ks * 4 + kc) ^ (brow & 7)) * 8)];
                acc[c] = __builtin_amdgcn_mfma_f32_16x16x32_bf16(af, bf, acc[c], 0, 0, 0);
            }
        }
    }

    #pragma unroll
    for (int c = 0; c < 4; ++c) {
        const int n = n0 + c * 16 + fr;
        const float bv = bias ? bias[n] : 0.0f;
        const bool do_vt = (VTp != nullptr) && (n >= vt_col0);
        #pragma unroll
        for (int i = 0; i < 4; ++i) {
            const long m = m0 + w * 16 + kc * 4 + i;
            float v = acc[c][i] * alpha + bv;
            if (RELU) v = fmaxf(v, 0.0f);
            if (OBF16) ((unsigned short*)Cv)[bz * sC + m * ldc + n] = f2bu(v);
            else       ((float*)Cv)[bz * sC + m * ldc + n] = v;
            if (do_vt) {
                const int vc = n - vt_col0;
                VTp[(long)(vc >> 6) * 65536 + (long)(vc & 63) * 1024 + m] = f2bu(v);
            }
        }
    }
}

// ------- fused attention + out-projection, in-block K-split ------------------
// Grid (64 q-tiles of 16 rows, 8 heads), 128 thr = 2 waves. Wave w processes
// K-tiles w*8..w*8+7 with wave-private 2-deep buffers (no main-loop barriers);
// exact flash merge via LDS; both waves split the 8 Wo chunks. ~74 KB LDS.
__global__ __launch_bounds__(128)
void attnp_k(const unsigned short* __restrict__ Qb, int qld,   // Q base/ld
             const unsigned short* __restrict__ Kb, int kld,   // K base/ld
             const unsigned short* __restrict__ VT,            // [8][64][1024]
             const unsigned short* __restrict__ wo,            // [512][512]
             unsigned short* __restrict__ SLABb)               // 8x[1024][512]
{
    __shared__ __align__(16) short U[36928];   // 73.9 KB
    short* Ks = U;                    // 4 x 4096 (wave w: bufs w*2+{0,1})
    short* Vs = U + 16384;            // 4 x 4096
    short* Ps = U + 32768;            // 2 x 1024 (P per wave; later po)
    float* Of = (float*)(U + 34816);  // 16 x 64 f32 (wave1 state)
    float* Ml = (float*)(U + 34816 + 2048);   // 16 x {m,l}
    const int qt = blockIdx.x;        // 0..63
    const int h  = blockIdx.y;
    const int tid = threadIdx.x;
    const int w  = tid >> 6;
    const int l  = tid & 63;
    const int fr = l & 15;
    const int kc = l >> 4;

    const int qrow = qt * 16 + fr;
    short8 qf[2];
    qf[0] = *(const short8*)(Qb + (long)qrow * qld + h * 64 + kc * 8);
    qf[1] = *(const short8*)(Qb + (long)qrow * qld + h * 64 + 32 + kc * 8);

    // wave w stages its own K-tile (w*8+t) alone: 16 gload16
    auto FILL = [&](int t, int lbuf) {
        const int kb  = (w * 8 + t) * 64;
        const int buf = w * 2 + lbuf;
        #pragma unroll
        for (int it = 0; it < 8; ++it) {
            const int row = it * 8 + (l >> 3);
            const int sl  = ((l & 7) ^ (row & 7)) * 8;
            gload16(Kb + (long)(kb + row) * kld + h * 64 + sl, Ks + buf * 4096 + it * 512);
            gload16(VT + (long)h * 65536 + (long)row * 1024 + kb + sl, Vs + buf * 4096 + it * 512);
        }
    };

    float m_i[4], l_i[4];
    f32x4 acc_o[4] = {};
    #pragma unroll
    for (int i = 0; i < 4; ++i) { m_i[i] = -1e30f; l_i[i] = 0.f; }

    short* ps = Ps + w * 1024;

    FILL(0, 0); FILL(1, 1);
    for (int t = 0; t < 8; ++t) {
        waitvm(t == 7 ? 0 : 16);          // own-wave loads only
        __builtin_amdgcn_sched_barrier(0);
        const int cb = w * 2 + (t & 1);

        f32x4 sacc[4] = {};
        #pragma unroll
        for (int ks = 0; ks < 2; ++ks) {
            #pragma unroll
            for (int c = 0; c < 4; ++c) {
                const int krow = c * 16 + fr;
                const short8 kf = *(const short8*)(Ks + cb * 4096 + krow * 64 + (((ks * 4 + kc) ^ (krow & 7)) * 8));
                sacc[c] = __builtin_amdgcn_mfma_f32_16x16x32_bf16(qf[ks], kf, sacc[c], 0, 0, 0);
            }
        }

        float p[4][4];
        #pragma unroll
        for (int i = 0; i < 4; ++i) {
            float tm = fmaxf(fmaxf(sacc[0][i], sacc[1][i]), fmaxf(sacc[2][i], sacc[3][i]));
            #pragma unroll
            for (int off = 8; off; off >>= 1) tm = fmaxf(tm, __shfl_xor(tm, off));
            tm *= 0.125f;
            const float mn = fmaxf(m_i[i], tm);
            const float sc = __expf(m_i[i] - mn);
            m_i[i] = mn;
            float ts = 0.f;
            #pragma unroll
            for (int c = 0; c < 4; ++c) { p[c][i] = __expf(sacc[c][i] * 0.125f - mn); ts += p[c][i]; }
            #pragma unroll
            for (int off = 8; off; off >>= 1) ts += __shfl_xor(ts, off);
            l_i[i] = l_i[i] * sc + ts;
            #pragma unroll
            for (int c = 0; c < 4; ++c) acc_o[c][i] *= sc;
        }

        #pragma unroll
        for (int c = 0; c < 4; ++c) {
            const int col = c * 16 + fr;
            #pragma unroll
            for (int i = 0; i < 4; ++i) {
                const int row = kc * 4 + i;
                ps[row * 64 + (((col >> 3) ^ (row & 7)) * 8) + (col & 7)] = (short)f2bu(p[c][i]);
            }
        }
        short8 pf[2];
        pf[0] = *(const short8*)(ps + fr * 64 + ((kc ^ (fr & 7)) * 8));
        pf[1] = *(const short8*)(ps + fr * 64 + (((4 + kc) ^ (fr & 7)) * 8));

        #pragma unroll
        for (int ks = 0; ks < 2; ++ks) {
            #pragma unroll
            for (int c = 0; c < 4; ++c) {
                const int drow = c * 16 + fr;
                const short8 vf = *(const short8*)(Vs + cb * 4096 + drow * 64 + (((ks * 4 + kc) ^ (drow & 7)) * 8));
                acc_o[c] = __builtin_amdgcn_mfma_f32_16x16x32_bf16(pf[ks], vf, acc_o[c], 0, 0, 0);
            }
        }
        // operands of the MFMAs above are already in regs (compiler lgkm waits),
        // so refilling the just-consumed buffer is safe.
        if (t + 2 < 8) FILL(t + 2, t & 1);
    }

    // -------- exact flash merge: wave1 publishes, wave0 combines -------------
    if (w == 1) {
        #pragma unroll
        for (int c = 0; c < 4; ++c)
            #pragma unroll
            for (int i = 0; i < 4; ++i)
                Of[(kc * 4 + i) * 64 + c * 16 + fr] = acc_o[c][i];
        if (fr == 0) {
            #pragma unroll
            for (int i = 0; i < 4; ++i) {
                Ml[(kc * 4 + i) * 2]     = m_i[i];
                Ml[(kc * 4 + i) * 2 + 1] = l_i[i];
            }
        }
    }
    __syncthreads();
    short* po = Ps;   // final O as bf16 A-frags (16x64)
    if (w == 0) {
        #pragma unroll
        for (int i = 0; i < 4; ++i) {
            const int row = kc * 4 + i;
            const float m1 = Ml[row * 2], l1 = Ml[row * 2 + 1];
            const float M  = fmaxf(m_i[i], m1);
            const float e0 = __expf(m_i[i] - M);
            const float e1 = __expf(m1 - M);
            const float inv = 1.0f / (e0 * l_i[i] + e1 * l1);
            #pragma unroll
            for (int c = 0; c < 4; ++c) {
                const int col = c * 16 + fr;
                const float o = e0 * acc_o[c][i] + e1 * Of[row * 64 + col];
                po[row * 64 + (((col >> 3) ^ (row & 7)) * 8) + (col & 7)] = (short)f2bu(o * inv);
            }
        }
    }
    __syncthreads();

    // -------- Wo epilogue: wave w handles chunks w*4..w*4+3 (wave-local) -----
    unsigned short* SLABh = SLABb + (long)h * 524288;
    auto WSTAGE = [&](int c8, int lbuf) {
        const int n0c = c8 * 64;
        const int buf = w * 2 + lbuf;
        #pragma unroll
        for (int it = 0; it < 8; ++it) {
            const int row = it * 8 + (l >> 3);
            const int sl  = ((l & 7) ^ (row & 7)) * 8;
            gload16(wo + (long)(n0c + row) * 512 + h * 64 + sl, Ks + buf * 4096 + it * 512);
        }
    };

    WSTAGE(w * 4, 0);
    for (int j = 0; j < 4; ++j) {
        if (j + 1 < 4) WSTAGE(w * 4 + j + 1, (j + 1) & 1);
        waitvm(j + 1 < 4 ? 8 : 0);
        __builtin_amdgcn_sched_barrier(0);
        const int buf = w * 2 + (j & 1);
        f32x4 a2[4] = {};
        #pragma unroll
        for (int ks = 0; ks < 2; ++ks) {
            const int q = ks * 4 + kc;
            const short8 af = *(const short8*)(po + fr * 64 + ((q ^ (fr & 7)) * 8));
            #pragma unroll
            for (int ct = 0; ct < 4; ++ct) {
                const int brn = ct * 16 + fr;
                const short8 bf = *(const short8*)(Ks + buf * 4096 + brn * 64 + ((q ^ (brn & 7)) * 8));
                a2[ct] = __builtin_amdgcn_mfma_f32_16x16x32_bf16(af, bf, a2[ct], 0, 0, 0);
            }
        }
        const int c8 = w * 4 + j;
        #pragma unroll
        for (int ct = 0; ct < 4; ++ct) {
            const int n = c8 * 64 + ct * 16 + fr;
            #pragma unroll
            for (int i = 0; i < 4; ++i)
                SLABh[(long)(qt * 16 + kc * 4 + i) * 512 + n] = f2bu(a2[ct][i]);
        }
    }
}

// ---- LayerNorm-as-merge: out = LN(x + sum_slabs + bias)*s + b ---------------
template<int NSLAB, bool SB16>
__global__ __launch_bounds__(256)
void ln_k(const float* __restrict__ x, const void* __restrict__ slab,
          const float* __restrict__ bias,
          const float* __restrict__ s, const float* __restrict__ b,
          float* __restrict__ out, unsigned short* __restrict__ outb)
{
    const int lane = threadIdx.x & 63;
    const int row  = (blockIdx.x << 2) + (threadIdx.x >> 6);
    const float* px = x + (long)row * 512;
    float v[8];
    float sum = 0.f;
    #pragma unroll
    for (int i = 0; i < 8; ++i) {
        const int j = lane + (i << 6);
        v[i] = px[j];
        #pragma unroll
        for (int t = 0; t < NSLAB; ++t) {
            if (SB16) v[i] += b2f(((const unsigned short*)slab)[(long)t * 524288 + (long)row * 512 + j]);
            else      v[i] += ((const float*)slab)[(long)t * 524288 + (long)row * 512 + j];
        }
        if (NSLAB > 0) v[i] += bias[j];
        sum += v[i];
    }
    #pragma unroll
    for (int off = 32; off; off >>= 1) sum += __shfl_xor(sum, off);
    const float m = sum * (1.0f / 512.0f);
    float s2 = 0.f;
    #pragma unroll
    for (int i = 0; i < 8; ++i) { const float d = v[i] - m; s2 += d * d; }
    #pragma unroll
    for (int off = 32; off; off >>= 1) s2 += __shfl_xor(s2, off);
    const float inv = rsqrtf(s2 * (1.0f / 512.0f) + 1e-5f);
    #pragma unroll
    for (int i = 0; i < 8; ++i) {
        const int j = lane + (i << 6);
        const float r = (v[i] - m) * inv * s[j] + b[j];
        out[(long)row * 512 + j] = r;
        if (outb) outb[(long)row * 512 + j] = f2bu(r);
    }
}

// -------- fused final LN + L2-normalize --------------------------------------
__global__ __launch_bounds__(256)
void lnl2_k(const float* __restrict__ x,
            const float* __restrict__ s, const float* __restrict__ b,
            float* __restrict__ out_attn, unsigned short* __restrict__ nb)
{
    const int lane = threadIdx.x & 63;
    const int row  = (blockIdx.x << 2) + (threadIdx.x >> 6);
    const float* px = x + (long)row * 512;
    float v[8];
    float sum = 0.f;
    #pragma unroll
    for (int i = 0; i < 8; ++i) { v[i] = px[lane + (i << 6)]; sum += v[i]; }
    #pragma unroll
    for (int off = 32; off; off >>= 1) sum += __shfl_xor(sum, off);
    const float m = sum * (1.0f / 512.0f);
    float s2 = 0.f;
    #pragma unroll
    for (int i = 0; i < 8; ++i) { const float d = v[i] - m; s2 += d * d; }
    #pragma unroll
    for (int off = 32; off; off >>= 1) s2 += __shfl_xor(s2, off);
    const float inv = rsqrtf(s2 * (1.0f / 512.0f) + 1e-5f);
    float nrm = 0.f;
    #pragma unroll
    for (int i = 0; i < 8; ++i) {
        const int j = lane + (i << 6);
        v[i] = (v[i] - m) * inv * s[j] + b[j];
        out_attn[(long)row * 512 + j] = v[i];
        nrm += v[i] * v[i];
    }
    #pragma unroll
    for (int off = 32; off; off >>= 1) nrm += __shfl_xor(nrm, off);
    const float rinv = rsqrtf(nrm);
    #pragma unroll
    for (int i = 0; i < 8; ++i)
        nb[(long)row * 512 + lane + (i << 6)] = f2bu(v[i] * rinv);
}

// -------- init: x -> MEMf, Yf (fp32) + MEMb, Yb (bf16) -----------------------
__global__ __launch_bounds__(256)
void init_k(const float* __restrict__ x, float* __restrict__ mf, float* __restrict__ yf,
            unsigned short* __restrict__ mb, unsigned short* __restrict__ yb)
{
    const long i = ((long)blockIdx.x * 256 + threadIdx.x) * 4;
    const float4 v = *(const float4*)(x + i);
    *(float4*)(mf + i) = v;
    *(float4*)(yf + i) = v;
    short4v s;
    s[0] = (short)f2bu(v.x); s[1] = (short)f2bu(v.y);
    s[2] = (short)f2bu(v.z); s[3] = (short)f2bu(v.w);
    *(short4v*)(mb + i) = s;
    *(short4v*)(yb + i) = s;
}

// ------------------------------ host side ------------------------------------
static void gemm3(hipStream_t st, bool relu, bool obf16,
                  const unsigned short* A, int lda,
                  const unsigned short* B, int ldb,
                  const float* bias, void* C, int ldc, long sC,
                  int M, int N, int K, float alpha, int batch,
                  unsigned short* VTp = nullptr, int vt_col0 = 0,
                  const unsigned short* A2 = nullptr, int a2_col = 0,
                  int kz = 0, long zB = 0, int zBias = 0, long zVT = 0)
{
    dim3 g(N / 64, M / 64, batch);
    if (obf16) {
        if (relu) gemm3_k<true,  true ><<<g, 256, 0, st>>>(A, A2, a2_col, lda, B, ldb, bias, C, ldc, sC, K, alpha, VTp, vt_col0, kz, zB, zBias, zVT);
        else      gemm3_k<false, true ><<<g, 256, 0, st>>>(A, A2, a2_col, lda, B, ldb, bias, C, ldc, sC, K, alpha, VTp, vt_col0, kz, zB, zBias, zVT);
    } else {
        if (relu) gemm3_k<true,  false><<<g, 256, 0, st>>>(A, A2, a2_col, lda, B, ldb, bias, C, ldc, sC, K, alpha, VTp, vt_col0, kz, zB, zBias, zVT);
        else      gemm3_k<false, false><<<g, 256, 0, st>>>(A, A2, a2_col, lda, B, ldb, bias, C, ldc, sC, K, alpha, VTp, vt_col0, kz, zB, zBias, zVT);
    }
}

extern "C" void kernel_launch(void* const* d_in, const int* in_sizes, int n_in,
                              void* d_out, int out_size, void* d_ws, size_t ws_size,
                              hipStream_t stream)
{
    const float* x            = (const float*)d_in[0];
    const float* enc_qkv_w    = (const float*)d_in[1];
    const float* enc_qkv_b    = (const float*)d_in[2];
    const float* enc_out_w    = (const float*)d_in[3];
    const float* enc_out_b    = (const float*)d_in[4];
    const float* enc_ff1_w    = (const float*)d_in[5];
    const float* enc_ff1_b    = (const float*)d_in[6];
    const float* enc_ff2_w    = (const float*)d_in[7];
    const float* enc_ff2_b    = (const float*)d_in[8];
    const float* enc_ln1_s    = (const float*)d_in[9];
    const float* enc_ln1_b    = (const float*)d_in[10];
    const float* enc_ln2_s    = (const float*)d_in[11];
    const float* enc_ln2_b    = (const float*)d_in[12];
    const float* dec_sa_qkv_w = (const float*)d_in[13];
    const float* dec_sa_qkv_b = (const float*)d_in[14];
    const float* dec_sa_out_w = (const float*)d_in[15];
    const float* dec_sa_out_b = (const float*)d_in[16];
    const float* dec_ca_qkv_w = (const float*)d_in[17];
    const float* dec_ca_qkv_b = (const float*)d_in[18];
    const float* dec_ca_out_w = (const float*)d_in[19];
    const float* dec_ca_out_b = (const float*)d_in[20];
    const float* dec_ff1_w    = (const float*)d_in[21];
    const float* dec_ff1_b    = (const float*)d_in[22];
    const float* dec_ff2_w    = (const float*)d_in[23];
    const float* dec_ff2_b    = (const float*)d_in[24];
    const float* dec_ln1_s    = (const float*)d_in[25];
    const float* dec_ln1_b    = (const float*)d_in[26];
    const float* dec_ln2_s    = (const float*)d_in[27];
    const float* dec_ln2_b    = (const float*)d_in[28];
    const float* dec_ln3_s    = (const float*)d_in[29];
    const float* dec_ln3_b    = (const float*)d_in[30];
    const float* enc_norm_s   = (const float*)d_in[31];
    const float* enc_norm_b   = (const float*)d_in[32];
    const float* dec_norm_s   = (const float*)d_in[33];
    const float* dec_norm_b   = (const float*)d_in[34];

    char* p = (char*)d_ws;
    auto alloc = [&](size_t bytes) -> char* {
        char* r = p; p += (bytes + 255) & ~(size_t)255; return r;
    };
    float*          MEMf = (float*)alloc(1024 * 512 * 4);
    float*          Yf   = (float*)alloc(1024 * 512 * 4);
    unsigned short* MEMb = (unsigned short*)alloc(1024 * 512 * 2);
    unsigned short* Yb   = (unsigned short*)alloc(1024 * 512 * 2);
    unsigned short* QKVb = (unsigned short*)alloc(1024 * 1536 * 2);
    unsigned short* VT   = (unsigned short*)alloc(8L * 64 * 1024 * 2);
    char*           SLAB = alloc(8L * 1024 * 512 * 2);
    unsigned short* F1b  = (unsigned short*)alloc(1024L * 2048 * 2);
    unsigned short* NBb  = (unsigned short*)alloc(1024 * 512 * 2);
    unsigned short* QB   = (unsigned short*)alloc(1024 * 512 * 2);        // CA Q
    unsigned short* KVCA = (unsigned short*)alloc(6L * 1024 * 1024 * 2);  // CA K (+V)
    unsigned short* VTCA = (unsigned short*)alloc(6L * 8 * 64 * 1024 * 2);// CA VT

    const float* wsrc[10] = {enc_qkv_w, enc_out_w, enc_ff1_w, enc_ff2_w,
                             dec_sa_qkv_w, dec_sa_out_w, dec_ca_qkv_w, dec_ca_out_w,
                             dec_ff1_w, dec_ff2_w};
    const long wper[10] = {1536L*512, 512L*512, 2048L*512, 512L*2048,
                           1536L*512, 512L*512, 1536L*512, 512L*512,
                           2048L*512, 512L*2048};
    long wtot = 0;
    for (int t = 0; t < 10; ++t) wtot += wper[t] * NLAY;

    const size_t used = (size_t)(p - (char*)d_ws);
    const bool preconv = (ws_size > used) && ((ws_size - used) >= (size_t)wtot * 2 + 4096);

    unsigned short* wpre[10] = {};
    unsigned short* slots[2] = {};
    int slot_ctr = 0;
    if (preconv) {
        WCvt wc;
        wc.cum[0] = 0;
        for (int t = 0; t < 10; ++t) {
            wpre[t] = (unsigned short*)alloc((size_t)wper[t] * NLAY * 2);
            wc.src[t] = wsrc[t];
            wc.dst[t] = wpre[t];
            wc.cum[t + 1] = wc.cum[t] + wper[t] * NLAY / 8;
        }
        f2ball_k<<<dim3(2048), 256, 0, stream>>>(wc);
    } else {
        slots[0] = (unsigned short*)alloc(2048L * 512 * 2);
        slots[1] = (unsigned short*)alloc(2048L * 512 * 2);
    }
    auto W = [&](int t, int layer) -> const unsigned short* {
        if (preconv) return wpre[t] + (long)layer * wper[t];
        unsigned short* dst = slots[(slot_ctr++) & 1];
        const long n = wper[t];
        long blocks = (n / 8 + 255) / 256; if (blocks > 2048) blocks = 2048;
        f2b_k<<<dim3((unsigned)blocks), 256, 0, stream>>>(wsrc[t] + (long)layer * wper[t], dst, n);
        return dst;
    };

    float* out_gram = (float*)d_out;
    float* out_attn = out_gram + 1024 * 1024;

    // self-attention: merged QKV GEMM -> attnp (self layout) -> LN<8>
    auto run_self = [&](const unsigned short* xb_in, int wt_qkv, int wt_o, int layer,
                        const float* bqkv, const float* obias,
                        const float* lns, const float* lnb,
                        float* xf, unsigned short* xb) {
        gemm3(stream, false, true, xb_in, 512, W(wt_qkv, layer), 512, bqkv,
              QKVb, 1536, 0, 1024, 1536, 512, 1.0f, 1, VT, 1024);
        attnp_k<<<dim3(64, 8), 128, 0, stream>>>(QKVb, 1536, QKVb + 512, 1536, VT,
                                                 W(wt_o, layer), (unsigned short*)SLAB);
        ln_k<8, true><<<256, 256, 0, stream>>>(xf, SLAB, obias, lns, lnb, xf, xb);
    };
    // FFN: FF1 (relu, bf16) -> FF2 split-K(4) fp32 slabs -> LN<4>
    auto run_ffn = [&](unsigned short* inb, int wt1, int wt2, int layer,
                       const float* b1, const float* f2bias,
                       const float* lns, const float* lnb,
                       float* xf, unsigned short* xb) {
        gemm3(stream, true, true, inb, 512, W(wt1, layer), 512, b1,
              F1b, 2048, 0, 1024, 2048, 512, 1.0f, 1);
        gemm3(stream, false, false, F1b, 2048, W(wt2, layer), 2048, nullptr,
              SLAB, 512, 524288, 1024, 512, 512, 1.0f, 4, nullptr, 0, nullptr, 0, 512);
        ln_k<4, false><<<256, 256, 0, stream>>>(xf, SLAB, f2bias, lns, lnb, xf, xb);
    };

    init_k<<<512, 256, 0, stream>>>(x, MEMf, Yf, MEMb, Yb);

    // ----------------------------- encoder -----------------------------------
    for (int i = 0; i < NLAY; ++i) {
        run_self(MEMb, 0, 1, i, enc_qkv_b + i * 1536, enc_out_b + i * 512,
                 enc_ln1_s + i * 512, enc_ln1_b + i * 512, MEMf, MEMb);
        run_ffn(MEMb, 2, 3, i, enc_ff1_b + i * 2048, enc_ff2_b + i * 512,
                enc_ln2_s + i * 512, enc_ln2_b + i * 512, MEMf, MEMb);
    }
    ln_k<0, false><<<256, 256, 0, stream>>>(MEMf, nullptr, nullptr, enc_norm_s, enc_norm_b, MEMf, MEMb);

    // -------- hoisted decoder cross-attn K/V (all 6 layers, 1 dispatch) ------
    if (preconv) {
        gemm3(stream, false, true, MEMb, 512, wpre[6] + 512L * 512, 512,
              dec_ca_qkv_b + 512, KVCA, 1024, 1024L * 1024,
              1024, 1024, 512, 1.0f, 6, VTCA, 512,
              nullptr, 0, 0, 1536L * 512, 1536, 524288L);
    }

    // ----------------------------- decoder -----------------------------------
    for (int i = 0; i < NLAY; ++i) {
        run_self(Yb, 4, 5, i, dec_sa_qkv_b + i * 1536, dec_sa_out_b + i * 512,
                 dec_ln1_s + i * 512, dec_ln1_b + i * 512, Yf, Yb);

        if (preconv) {
            // CA: Q-only GEMM -> attnp (hoisted K/V layout) -> LN<8>
            gemm3(stream, false, true, Yb, 512, W(6, i), 512, dec_ca_qkv_b + i * 1536,
                  QB, 512, 0, 1024, 512, 512, 1.0f, 1);
            attnp_k<<<dim3(64, 8), 128, 0, stream>>>(QB, 512,
                    KVCA + (long)i * 1024 * 1024, 1024, VTCA + (long)i * 524288,
                    W(7, i), (unsigned short*)SLAB);
        } else {
            gemm3(stream, false, true, Yb, 512, W(6, i), 512, dec_ca_qkv_b + i * 1536,
                  QKVb, 1536, 0, 1024, 1536, 512, 1.0f, 1, VT, 1024, MEMb, 512);
            attnp_k<<<dim3(64, 8), 128, 0, stream>>>(QKVb, 1536, QKVb + 512, 1536, VT,
                                                     W(7, i), (unsigned short*)SLAB);
        }
        ln_k<8, true><<<256, 256, 0, stream>>>(Yf, SLAB, dec_ca_out_b + i * 512,
                                               dec_ln2_s + i * 512, dec_ln2_b + i * 512, Yf, Yb);

        run_ffn(Yb, 8, 9, i, dec_ff1_b + i * 2048, dec_ff2_b + i * 512,
                dec_ln3_s + i * 512, dec_ln3_b + i * 512, Yf, Yb);
    }

    // final: attention_out + n = rownorm (fused), gram = n@n^T
    lnl2_k<<<256, 256, 0, stream>>>(Yf, dec_norm_s, dec_norm_b, out_attn, NBb);
    gemm3(stream, false, false, NBb, 512, NBb, 512, nullptr,
          out_gram, 1024, 0, 1024, 1024, 512, 1.0f, 1);
}

// Round 15
// 952.834 us; speedup vs baseline: 1.3061x; 1.0803x over previous
//
#include <hip/hip_runtime.h>

// MyTransformer: 6-enc + 6-dec, S=1024, D=512, H=8x64, FF=2048.
// Round 14: round-13 structure + (1) FF2 slabs bf16, (2) enc_norm / final
// LN+L2 folded into the FF2-LN dispatches (FIN templates), (3) VT written via
// LDS transpose (coalesced) instead of 2B scatter.

#define NLAY 6

typedef __attribute__((ext_vector_type(8))) short short8;
typedef __attribute__((ext_vector_type(4))) short short4v;
typedef __attribute__((ext_vector_type(4))) float f32x4;

typedef __attribute__((address_space(3))) short lds_short;
typedef __attribute__((address_space(1))) const unsigned short g_ushort;

__device__ __forceinline__ void gload16(const unsigned short* g, short* l) {
    __builtin_amdgcn_global_load_lds((g_ushort*)g, (lds_short*)l, 16, 0, 0);
}

__device__ __forceinline__ void waitvm(int n) {   // wave-uniform literal waits
    if (n == 0)       asm volatile("s_waitcnt vmcnt(0)" ::: "memory");
    else if (n == 4)  asm volatile("s_waitcnt vmcnt(4)" ::: "memory");
    else if (n == 8)  asm volatile("s_waitcnt vmcnt(8)" ::: "memory");
    else              asm volatile("s_waitcnt vmcnt(16)" ::: "memory");
}

__device__ inline unsigned short f2bu(float x) {
    unsigned u = __builtin_bit_cast(unsigned, x);
    unsigned r = (u + 0x7fffu + ((u >> 16) & 1u)) >> 16;   // RNE
    return (unsigned short)r;
}

__device__ inline float b2f(unsigned short u) {
    return __builtin_bit_cast(float, (unsigned)u << 16);
}

// ------------- fp32 -> bf16 weight cvt: flat balanced grid, 1 dispatch -------
struct WCvt {
    const float* src[10];
    unsigned short* dst[10];
    long cum[11];           // prefix sums in 8-element chunks
};

__global__ __launch_bounds__(256)
void f2ball_k(WCvt wc)
{
    const long total = wc.cum[10];
    for (long c = (long)blockIdx.x * 256 + threadIdx.x; c < total;
         c += (long)gridDim.x * 256) {
        int t = 0;
        #pragma unroll
        for (int i = 1; i < 10; ++i) if (c >= wc.cum[i]) t = i;
        const long o = (c - wc.cum[t]) * 8;
        const float* s = wc.src[t];
        unsigned short* d = wc.dst[t];
        const float4 a = *(const float4*)(s + o);
        const float4 b = *(const float4*)(s + o + 4);
        short8 v;
        v[0] = (short)f2bu(a.x); v[1] = (short)f2bu(a.y);
        v[2] = (short)f2bu(a.z); v[3] = (short)f2bu(a.w);
        v[4] = (short)f2bu(b.x); v[5] = (short)f2bu(b.y);
        v[6] = (short)f2bu(b.z); v[7] = (short)f2bu(b.w);
        *(short8*)(d + o) = v;
    }
}

__global__ __launch_bounds__(256)
void f2b_k(const float* __restrict__ s, unsigned short* __restrict__ d, long n)
{
    const long stride = (long)gridDim.x * 256;
    for (long i = (long)blockIdx.x * 256 + threadIdx.x; i * 8 < n; i += stride) {
        const long o = i * 8;
        const float4 a = *(const float4*)(s + o);
        const float4 b = *(const float4*)(s + o + 4);
        short8 v;
        v[0] = (short)f2bu(a.x); v[1] = (short)f2bu(a.y);
        v[2] = (short)f2bu(a.z); v[3] = (short)f2bu(a.w);
        v[4] = (short)f2bu(b.x); v[5] = (short)f2bu(b.y);
        v[6] = (short)f2bu(b.z); v[7] = (short)f2bu(b.w);
        *(short8*)(d + o) = v;
    }
}

// ---------------- 4-wave MFMA GEMM: C = alpha * A @ B^T + bias ---------------
// 64x64 tile, BK=64, 3-buffer gload_lds pipeline (48 KB -> 3 blocks/CU).
// Per-z: A/B += z*kz (split-K); B += z*zB, bias += z*zBias, VT += z*zVT,
// C += z*sC. A2: merged-input column split. VTp: V-transpose (cols >= vt_col0)
// written via LDS transpose (coalesced 16-short rows), not scatter.
template<bool RELU, bool OBF16>
__global__ __launch_bounds__(256)
void gemm3_k(const unsigned short* __restrict__ A,
             const unsigned short* __restrict__ A2, int a2_col, int lda,
             const unsigned short* __restrict__ B, int ldb,
             const float* __restrict__ bias,
             void* __restrict__ Cv, int ldc, long sC,
             int K, float alpha,
             unsigned short* __restrict__ VTp, int vt_col0, int kz,
             long zB, int zBias, long zVT)
{
    __shared__ __align__(16) short As[3][4096];
    __shared__ __align__(16) short Bs[3][4096];
    const int bz = blockIdx.z;
    const int m0 = blockIdx.y * 64;
    const int n0 = blockIdx.x * 64;
    if (A2 && n0 >= a2_col) A = A2;
    A += (long)bz * kz;
    B += (long)bz * kz + (long)bz * zB;
    if (bias) bias += (long)bz * zBias;
    if (VTp)  VTp  += (long)bz * zVT;
    const int tid = threadIdx.x;
    const int w  = tid >> 6;
    const int l  = tid & 63;
    const int fr = l & 15;
    const int kc = l >> 4;

    f32x4 acc[4] = {};
    const int T = K >> 6;

    auto FILL = [&](int t, int buf) {
        const int k0 = t * 64;
        #pragma unroll
        for (int it = 0; it < 2; ++it) {
            const int row = w * 16 + it * 8 + (l >> 3);
            const int sl  = ((l & 7) ^ (row & 7)) * 8;
            gload16(A + (long)(m0 + row) * lda + k0 + sl, &As[buf][(w * 16 + it * 8) * 64]);
            gload16(B + (long)(n0 + row) * ldb + k0 + sl, &Bs[buf][(w * 16 + it * 8) * 64]);
        }
    };

    FILL(0, 0);
    if (T > 1) FILL(1, 1);
    for (int t = 0; t < T; ++t) {
        waitvm(t + 1 < T ? 4 : 0);
        __builtin_amdgcn_sched_barrier(0);
        __builtin_amdgcn_s_barrier();
        if (t + 2 < T) FILL(t + 2, (t + 2) % 3);
        const int cb = t % 3;
        #pragma unroll
        for (int ks = 0; ks < 2; ++ks) {
            const int arow = w * 16 + fr;
            const short8 af = *(const short8*)&As[cb][arow * 64 + (((ks * 4 + kc) ^ (arow & 7)) * 8)];
            #pragma unroll
            for (int c = 0; c < 4; ++c) {
                const int brow = c * 16 + fr;
                const short8 bf = *(const short8*)&Bs[cb][brow * 64 + (((ks * 4 + kc) ^ (brow & 7)) * 8)];
                acc[c] = __builtin_amdgcn_mfma_f32_16x16x32_bf16(af, bf, acc[c], 0, 0, 0);
            }
        }
    }

    #pragma unroll
    for (int c = 0; c < 4; ++c) {
        const int n = n0 + c * 16 + fr;
        const float bv = bias ? bias[n] : 0.0f;
        #pragma unroll
        for (int i = 0; i < 4; ++i) {
            const long m = m0 + w * 16 + kc * 4 + i;
            float v = acc[c][i] * alpha + bv;
            if (RELU) v = fmaxf(v, 0.0f);
            if (OBF16) ((unsigned short*)Cv)[bz * sC + m * ldc + n] = f2bu(v);
            else       ((float*)Cv)[bz * sC + m * ldc + n] = v;
        }
    }

    // ---- V-transpose via LDS (block-uniform): coalesced 16-short rows ----
    if (VTp != nullptr && n0 >= vt_col0) {
        __syncthreads();                      // K-loop LDS retired
        short* TB = &As[0][0];                // 64 x 72 pitch (4608 shorts)
        #pragma unroll
        for (int c = 0; c < 4; ++c) {
            const int n = n0 + c * 16 + fr;
            const float bv = bias ? bias[n] : 0.0f;
            const int d = (n - vt_col0) & 63;
            #pragma unroll
            for (int i = 0; i < 4; ++i) {
                float v = acc[c][i] * alpha + bv;
                if (RELU) v = fmaxf(v, 0.0f);
                TB[d * 72 + w * 16 + kc * 4 + i] = (short)f2bu(v);
            }
        }
        __syncthreads();
        const long hh = (long)((n0 - vt_col0) >> 6);
        const int d  = tid >> 2;
        const int mc = (tid & 3) * 16;
        const short8 o0 = *(const short8*)&TB[d * 72 + mc];
        const short8 o1 = *(const short8*)&TB[d * 72 + mc + 8];
        unsigned short* dst = VTp + hh * 65536 + (long)d * 1024 + m0 + mc;
        *(short8*)dst = o0;
        *(short8*)(dst + 8) = o1;
    }
}

// ------- fused attention + out-projection, in-block K-split ------------------
// (round-13 proven kernel, unchanged)
__global__ __launch_bounds__(128)
void attnp_k(const unsigned short* __restrict__ Qb, int qld,
             const unsigned short* __restrict__ Kb, int kld,
             const unsigned short* __restrict__ VT,
             const unsigned short* __restrict__ wo,
             unsigned short* __restrict__ SLABb)
{
    __shared__ __align__(16) short U[36928];
    short* Ks = U;
    short* Vs = U + 16384;
    short* Ps = U + 32768;
    float* Of = (float*)(U + 34816);
    float* Ml = (float*)(U + 34816 + 2048);
    const int qt = blockIdx.x;
    const int h  = blockIdx.y;
    const int tid = threadIdx.x;
    const int w  = tid >> 6;
    const int l  = tid & 63;
    const int fr = l & 15;
    const int kc = l >> 4;

    const int qrow = qt * 16 + fr;
    short8 qf[2];
    qf[0] = *(const short8*)(Qb + (long)qrow * qld + h * 64 + kc * 8);
    qf[1] = *(const short8*)(Qb + (long)qrow * qld + h * 64 + 32 + kc * 8);

    auto FILL = [&](int t, int lbuf) {
        const int kb  = (w * 8 + t) * 64;
        const int buf = w * 2 + lbuf;
        #pragma unroll
        for (int it = 0; it < 8; ++it) {
            const int row = it * 8 + (l >> 3);
            const int sl  = ((l & 7) ^ (row & 7)) * 8;
            gload16(Kb + (long)(kb + row) * kld + h * 64 + sl, Ks + buf * 4096 + it * 512);
            gload16(VT + (long)h * 65536 + (long)row * 1024 + kb + sl, Vs + buf * 4096 + it * 512);
        }
    };

    float m_i[4], l_i[4];
    f32x4 acc_o[4] = {};
    #pragma unroll
    for (int i = 0; i < 4; ++i) { m_i[i] = -1e30f; l_i[i] = 0.f; }

    short* ps = Ps + w * 1024;

    FILL(0, 0); FILL(1, 1);
    for (int t = 0; t < 8; ++t) {
        waitvm(t == 7 ? 0 : 16);
        __builtin_amdgcn_sched_barrier(0);
        const int cb = w * 2 + (t & 1);

        f32x4 sacc[4] = {};
        #pragma unroll
        for (int ks = 0; ks < 2; ++ks) {
            #pragma unroll
            for (int c = 0; c < 4; ++c) {
                const int krow = c * 16 + fr;
                const short8 kf = *(const short8*)(Ks + cb * 4096 + krow * 64 + (((ks * 4 + kc) ^ (krow & 7)) * 8));
                sacc[c] = __builtin_amdgcn_mfma_f32_16x16x32_bf16(qf[ks], kf, sacc[c], 0, 0, 0);
            }
        }

        float p[4][4];
        #pragma unroll
        for (int i = 0; i < 4; ++i) {
            float tm = fmaxf(fmaxf(sacc[0][i], sacc[1][i]), fmaxf(sacc[2][i], sacc[3][i]));
            #pragma unroll
            for (int off = 8; off; off >>= 1) tm = fmaxf(tm, __shfl_xor(tm, off));
            tm *= 0.125f;
            const float mn = fmaxf(m_i[i], tm);
            const float sc = __expf(m_i[i] - mn);
            m_i[i] = mn;
            float ts = 0.f;
            #pragma unroll
            for (int c = 0; c < 4; ++c) { p[c][i] = __expf(sacc[c][i] * 0.125f - mn); ts += p[c][i]; }
            #pragma unroll
            for (int off = 8; off; off >>= 1) ts += __shfl_xor(ts, off);
            l_i[i] = l_i[i] * sc + ts;
            #pragma unroll
            for (int c = 0; c < 4; ++c) acc_o[c][i] *= sc;
        }

        #pragma unroll
        for (int c = 0; c < 4; ++c) {
            const int col = c * 16 + fr;
            #pragma unroll
            for (int i = 0; i < 4; ++i) {
                const int row = kc * 4 + i;
                ps[row * 64 + (((col >> 3) ^ (row & 7)) * 8) + (col & 7)] = (short)f2bu(p[c][i]);
            }
        }
        short8 pf[2];
        pf[0] = *(const short8*)(ps + fr * 64 + ((kc ^ (fr & 7)) * 8));
        pf[1] = *(const short8*)(ps + fr * 64 + (((4 + kc) ^ (fr & 7)) * 8));

        #pragma unroll
        for (int ks = 0; ks < 2; ++ks) {
            #pragma unroll
            for (int c = 0; c < 4; ++c) {
                const int drow = c * 16 + fr;
                const short8 vf = *(const short8*)(Vs + cb * 4096 + drow * 64 + (((ks * 4 + kc) ^ (drow & 7)) * 8));
                acc_o[c] = __builtin_amdgcn_mfma_f32_16x16x32_bf16(pf[ks], vf, acc_o[c], 0, 0, 0);
            }
        }
        if (t + 2 < 8) FILL(t + 2, t & 1);
    }

    if (w == 1) {
        #pragma unroll
        for (int c = 0; c < 4; ++c)
            #pragma unroll
            for (int i = 0; i < 4; ++i)
                Of[(kc * 4 + i) * 64 + c * 16 + fr] = acc_o[c][i];
        if (fr == 0) {
            #pragma unroll
            for (int i = 0; i < 4; ++i) {
                Ml[(kc * 4 + i) * 2]     = m_i[i];
                Ml[(kc * 4 + i) * 2 + 1] = l_i[i];
            }
        }
    }
    __syncthreads();
    short* po = Ps;
    if (w == 0) {
        #pragma unroll
        for (int i = 0; i < 4; ++i) {
            const int row = kc * 4 + i;
            const float m1 = Ml[row * 2], l1 = Ml[row * 2 + 1];
            const float M  = fmaxf(m_i[i], m1);
            const float e0 = __expf(m_i[i] - M);
            const float e1 = __expf(m1 - M);
            const float inv = 1.0f / (e0 * l_i[i] + e1 * l1);
            #pragma unroll
            for (int c = 0; c < 4; ++c) {
                const int col = c * 16 + fr;
                const float o = e0 * acc_o[c][i] + e1 * Of[row * 64 + col];
                po[row * 64 + (((col >> 3) ^ (row & 7)) * 8) + (col & 7)] = (short)f2bu(o * inv);
            }
        }
    }
    __syncthreads();

    unsigned short* SLABh = SLABb + (long)h * 524288;
    auto WSTAGE = [&](int c8, int lbuf) {
        const int n0c = c8 * 64;
        const int buf = w * 2 + lbuf;
        #pragma unroll
        for (int it = 0; it < 8; ++it) {
            const int row = it * 8 + (l >> 3);
            const int sl  = ((l & 7) ^ (row & 7)) * 8;
            gload16(wo + (long)(n0c + row) * 512 + h * 64 + sl, Ks + buf * 4096 + it * 512);
        }
    };

    WSTAGE(w * 4, 0);
    for (int j = 0; j < 4; ++j) {
        if (j + 1 < 4) WSTAGE(w * 4 + j + 1, (j + 1) & 1);
        waitvm(j + 1 < 4 ? 8 : 0);
        __builtin_amdgcn_sched_barrier(0);
        const int buf = w * 2 + (j & 1);
        f32x4 a2[4] = {};
        #pragma unroll
        for (int ks = 0; ks < 2; ++ks) {
            const int q = ks * 4 + kc;
            const short8 af = *(const short8*)(po + fr * 64 + ((q ^ (fr & 7)) * 8));
            #pragma unroll
            for (int ct = 0; ct < 4; ++ct) {
                const int brn = ct * 16 + fr;
                const short8 bf = *(const short8*)(Ks + buf * 4096 + brn * 64 + ((q ^ (brn & 7)) * 8));
                a2[ct] = __builtin_amdgcn_mfma_f32_16x16x32_bf16(af, bf, a2[ct], 0, 0, 0);
            }
        }
        const int c8 = w * 4 + j;
        #pragma unroll
        for (int ct = 0; ct < 4; ++ct) {
            const int n = c8 * 64 + ct * 16 + fr;
            #pragma unroll
            for (int i = 0; i < 4; ++i)
                SLABh[(long)(qt * 16 + kc * 4 + i) * 512 + n] = f2bu(a2[ct][i]);
        }
    }
}

// ---- LayerNorm-as-merge with optional second-LN fold ------------------------
// FIN=0: out=r fp32+bf16. FIN=1: r2=LN(r)*s2+b2 -> outb only.
// FIN=2: r2 -> oattn fp32 + L2-normalize -> nbb bf16.
template<int NSLAB, bool SB16, int FIN>
__global__ __launch_bounds__(256)
void ln_k(const float* __restrict__ x, const void* __restrict__ slab,
          const float* __restrict__ bias,
          const float* __restrict__ s, const float* __restrict__ b,
          float* __restrict__ outf, unsigned short* __restrict__ outb,
          const float* __restrict__ s2, const float* __restrict__ b2,
          float* __restrict__ oattn, unsigned short* __restrict__ nbb)
{
    const int lane = threadIdx.x & 63;
    const int row  = (blockIdx.x << 2) + (threadIdx.x >> 6);
    const float* px = x + (long)row * 512;
    float v[8];
    float sum = 0.f;
    #pragma unroll
    for (int i = 0; i < 8; ++i) {
        const int j = lane + (i << 6);
        v[i] = px[j];
        #pragma unroll
        for (int t = 0; t < NSLAB; ++t) {
            if (SB16) v[i] += b2f(((const unsigned short*)slab)[(long)t * 524288 + (long)row * 512 + j]);
            else      v[i] += ((const float*)slab)[(long)t * 524288 + (long)row * 512 + j];
        }
        if (NSLAB > 0) v[i] += bias[j];
        sum += v[i];
    }
    #pragma unroll
    for (int off = 32; off; off >>= 1) sum += __shfl_xor(sum, off);
    const float m = sum * (1.0f / 512.0f);
    float s2v = 0.f;
    #pragma unroll
    for (int i = 0; i < 8; ++i) { const float d = v[i] - m; s2v += d * d; }
    #pragma unroll
    for (int off = 32; off; off >>= 1) s2v += __shfl_xor(s2v, off);
    const float inv = rsqrtf(s2v * (1.0f / 512.0f) + 1e-5f);
    float r[8];
    #pragma unroll
    for (int i = 0; i < 8; ++i) {
        const int j = lane + (i << 6);
        r[i] = (v[i] - m) * inv * s[j] + b[j];
    }
    if (FIN == 0) {
        #pragma unroll
        for (int i = 0; i < 8; ++i) {
            const int j = lane + (i << 6);
            outf[(long)row * 512 + j] = r[i];
            outb[(long)row * 512 + j] = f2bu(r[i]);
        }
    } else {
        float sum2 = 0.f;
        #pragma unroll
        for (int i = 0; i < 8; ++i) sum2 += r[i];
        #pragma unroll
        for (int off = 32; off; off >>= 1) sum2 += __shfl_xor(sum2, off);
        const float m2 = sum2 * (1.0f / 512.0f);
        float q2 = 0.f;
        #pragma unroll
        for (int i = 0; i < 8; ++i) { const float d = r[i] - m2; q2 += d * d; }
        #pragma unroll
        for (int off = 32; off; off >>= 1) q2 += __shfl_xor(q2, off);
        const float inv2 = rsqrtf(q2 * (1.0f / 512.0f) + 1e-5f);
        if (FIN == 1) {
            #pragma unroll
            for (int i = 0; i < 8; ++i) {
                const int j = lane + (i << 6);
                outb[(long)row * 512 + j] = f2bu((r[i] - m2) * inv2 * s2[j] + b2[j]);
            }
        } else {
            float r2[8];
            float nrm = 0.f;
            #pragma unroll
            for (int i = 0; i < 8; ++i) {
                const int j = lane + (i << 6);
                r2[i] = (r[i] - m2) * inv2 * s2[j] + b2[j];
                oattn[(long)row * 512 + j] = r2[i];
                nrm += r2[i] * r2[i];
            }
            #pragma unroll
            for (int off = 32; off; off >>= 1) nrm += __shfl_xor(nrm, off);
            const float rinv = rsqrtf(nrm);
            #pragma unroll
            for (int i = 0; i < 8; ++i)
                nbb[(long)row * 512 + lane + (i << 6)] = f2bu(r2[i] * rinv);
        }
    }
}

// -------- init: x -> MEMf, Yf (fp32) + MEMb, Yb (bf16) -----------------------
__global__ __launch_bounds__(256)
void init_k(const float* __restrict__ x, float* __restrict__ mf, float* __restrict__ yf,
            unsigned short* __restrict__ mb, unsigned short* __restrict__ yb)
{
    const long i = ((long)blockIdx.x * 256 + threadIdx.x) * 4;
    const float4 v = *(const float4*)(x + i);
    *(float4*)(mf + i) = v;
    *(float4*)(yf + i) = v;
    short4v s;
    s[0] = (short)f2bu(v.x); s[1] = (short)f2bu(v.y);
    s[2] = (short)f2bu(v.z); s[3] = (short)f2bu(v.w);
    *(short4v*)(mb + i) = s;
    *(short4v*)(yb + i) = s;
}

// ------------------------------ host side ------------------------------------
static void gemm3(hipStream_t st, bool relu, bool obf16,
                  const unsigned short* A, int lda,
                  const unsigned short* B, int ldb,
                  const float* bias, void* C, int ldc, long sC,
                  int M, int N, int K, float alpha, int batch,
                  unsigned short* VTp = nullptr, int vt_col0 = 0,
                  const unsigned short* A2 = nullptr, int a2_col = 0,
                  int kz = 0, long zB = 0, int zBias = 0, long zVT = 0)
{
    dim3 g(N / 64, M / 64, batch);
    if (obf16) {
        if (relu) gemm3_k<true,  true ><<<g, 256, 0, st>>>(A, A2, a2_col, lda, B, ldb, bias, C, ldc, sC, K, alpha, VTp, vt_col0, kz, zB, zBias, zVT);
        else      gemm3_k<false, true ><<<g, 256, 0, st>>>(A, A2, a2_col, lda, B, ldb, bias, C, ldc, sC, K, alpha, VTp, vt_col0, kz, zB, zBias, zVT);
    } else {
        if (relu) gemm3_k<true,  false><<<g, 256, 0, st>>>(A, A2, a2_col, lda, B, ldb, bias, C, ldc, sC, K, alpha, VTp, vt_col0, kz, zB, zBias, zVT);
        else      gemm3_k<false, false><<<g, 256, 0, st>>>(A, A2, a2_col, lda, B, ldb, bias, C, ldc, sC, K, alpha, VTp, vt_col0, kz, zB, zBias, zVT);
    }
}

extern "C" void kernel_launch(void* const* d_in, const int* in_sizes, int n_in,
                              void* d_out, int out_size, void* d_ws, size_t ws_size,
                              hipStream_t stream)
{
    const float* x            = (const float*)d_in[0];
    const float* enc_qkv_w    = (const float*)d_in[1];
    const float* enc_qkv_b    = (const float*)d_in[2];
    const float* enc_out_w    = (const float*)d_in[3];
    const float* enc_out_b    = (const float*)d_in[4];
    const float* enc_ff1_w    = (const float*)d_in[5];
    const float* enc_ff1_b    = (const float*)d_in[6];
    const float* enc_ff2_w    = (const float*)d_in[7];
    const float* enc_ff2_b    = (const float*)d_in[8];
    const float* enc_ln1_s    = (const float*)d_in[9];
    const float* enc_ln1_b    = (const float*)d_in[10];
    const float* enc_ln2_s    = (const float*)d_in[11];
    const float* enc_ln2_b    = (const float*)d_in[12];
    const float* dec_sa_qkv_w = (const float*)d_in[13];
    const float* dec_sa_qkv_b = (const float*)d_in[14];
    const float* dec_sa_out_w = (const float*)d_in[15];
    const float* dec_sa_out_b = (const float*)d_in[16];
    const float* dec_ca_qkv_w = (const float*)d_in[17];
    const float* dec_ca_qkv_b = (const float*)d_in[18];
    const float* dec_ca_out_w = (const float*)d_in[19];
    const float* dec_ca_out_b = (const float*)d_in[20];
    const float* dec_ff1_w    = (const float*)d_in[21];
    const float* dec_ff1_b    = (const float*)d_in[22];
    const float* dec_ff2_w    = (const float*)d_in[23];
    const float* dec_ff2_b    = (const float*)d_in[24];
    const float* dec_ln1_s    = (const float*)d_in[25];
    const float* dec_ln1_b    = (const float*)d_in[26];
    const float* dec_ln2_s    = (const float*)d_in[27];
    const float* dec_ln2_b    = (const float*)d_in[28];
    const float* dec_ln3_s    = (const float*)d_in[29];
    const float* dec_ln3_b    = (const float*)d_in[30];
    const float* enc_norm_s   = (const float*)d_in[31];
    const float* enc_norm_b   = (const float*)d_in[32];
    const float* dec_norm_s   = (const float*)d_in[33];
    const float* dec_norm_b   = (const float*)d_in[34];

    char* p = (char*)d_ws;
    auto alloc = [&](size_t bytes) -> char* {
        char* r = p; p += (bytes + 255) & ~(size_t)255; return r;
    };
    float*          MEMf = (float*)alloc(1024 * 512 * 4);
    float*          Yf   = (float*)alloc(1024 * 512 * 4);
    unsigned short* MEMb = (unsigned short*)alloc(1024 * 512 * 2);
    unsigned short* Yb   = (unsigned short*)alloc(1024 * 512 * 2);
    unsigned short* QKVb = (unsigned short*)alloc(1024 * 1536 * 2);
    unsigned short* VT   = (unsigned short*)alloc(8L * 64 * 1024 * 2);
    char*           SLAB = alloc(8L * 1024 * 512 * 2);   // 8 bf16 slabs
    unsigned short* F1b  = (unsigned short*)alloc(1024L * 2048 * 2);
    unsigned short* NBb  = (unsigned short*)alloc(1024 * 512 * 2);
    unsigned short* QB   = (unsigned short*)alloc(1024 * 512 * 2);
    unsigned short* KVCA = (unsigned short*)alloc(6L * 1024 * 1024 * 2);
    unsigned short* VTCA = (unsigned short*)alloc(6L * 8 * 64 * 1024 * 2);

    const float* wsrc[10] = {enc_qkv_w, enc_out_w, enc_ff1_w, enc_ff2_w,
                             dec_sa_qkv_w, dec_sa_out_w, dec_ca_qkv_w, dec_ca_out_w,
                             dec_ff1_w, dec_ff2_w};
    const long wper[10] = {1536L*512, 512L*512, 2048L*512, 512L*2048,
                           1536L*512, 512L*512, 1536L*512, 512L*512,
                           2048L*512, 512L*2048};
    long wtot = 0;
    for (int t = 0; t < 10; ++t) wtot += wper[t] * NLAY;

    const size_t used = (size_t)(p - (char*)d_ws);
    const bool preconv = (ws_size > used) && ((ws_size - used) >= (size_t)wtot * 2 + 4096);

    unsigned short* wpre[10] = {};
    unsigned short* slots[2] = {};
    int slot_ctr = 0;
    if (preconv) {
        WCvt wc;
        wc.cum[0] = 0;
        for (int t = 0; t < 10; ++t) {
            wpre[t] = (unsigned short*)alloc((size_t)wper[t] * NLAY * 2);
            wc.src[t] = wsrc[t];
            wc.dst[t] = wpre[t];
            wc.cum[t + 1] = wc.cum[t] + wper[t] * NLAY / 8;
        }
        f2ball_k<<<dim3(2048), 256, 0, stream>>>(wc);
    } else {
        slots[0] = (unsigned short*)alloc(2048L * 512 * 2);
        slots[1] = (unsigned short*)alloc(2048L * 512 * 2);
    }
    auto W = [&](int t, int layer) -> const unsigned short* {
        if (preconv) return wpre[t] + (long)layer * wper[t];
        unsigned short* dst = slots[(slot_ctr++) & 1];
        const long n = wper[t];
        long blocks = (n / 8 + 255) / 256; if (blocks > 2048) blocks = 2048;
        f2b_k<<<dim3((unsigned)blocks), 256, 0, stream>>>(wsrc[t] + (long)layer * wper[t], dst, n);
        return dst;
    };

    float* out_gram = (float*)d_out;
    float* out_attn = out_gram + 1024 * 1024;

    auto run_self = [&](const unsigned short* xb_in, int wt_qkv, int wt_o, int layer,
                        const float* bqkv, const float* obias,
                        const float* lns, const float* lnb,
                        float* xf, unsigned short* xb) {
        gemm3(stream, false, true, xb_in, 512, W(wt_qkv, layer), 512, bqkv,
              QKVb, 1536, 0, 1024, 1536, 512, 1.0f, 1, VT, 1024);
        attnp_k<<<dim3(64, 8), 128, 0, stream>>>(QKVb, 1536, QKVb + 512, 1536, VT,
                                                 W(wt_o, layer), (unsigned short*)SLAB);
        ln_k<8, true, 0><<<256, 256, 0, stream>>>(xf, SLAB, obias, lns, lnb, xf, xb,
                                                  nullptr, nullptr, nullptr, nullptr);
    };
    // FFN: FF1 (relu, bf16) -> FF2 split-K(4) bf16 slabs -> LN<4> (fin variants)
    auto run_ffn = [&](unsigned short* inb, int wt1, int wt2, int layer,
                       const float* b1, const float* f2bias,
                       const float* lns, const float* lnb,
                       float* xf, unsigned short* xb, int fin,
                       const float* s2, const float* b2) {
        gemm3(stream, true, true, inb, 512, W(wt1, layer), 512, b1,
              F1b, 2048, 0, 1024, 2048, 512, 1.0f, 1);
        gemm3(stream, false, true, F1b, 2048, W(wt2, layer), 2048, nullptr,
              SLAB, 512, 524288, 1024, 512, 512, 1.0f, 4, nullptr, 0, nullptr, 0, 512);
        if (fin == 0)
            ln_k<4, true, 0><<<256, 256, 0, stream>>>(xf, SLAB, f2bias, lns, lnb, xf, xb,
                                                      nullptr, nullptr, nullptr, nullptr);
        else if (fin == 1)
            ln_k<4, true, 1><<<256, 256, 0, stream>>>(xf, SLAB, f2bias, lns, lnb, xf, xb,
                                                      s2, b2, nullptr, nullptr);
        else
            ln_k<4, true, 2><<<256, 256, 0, stream>>>(xf, SLAB, f2bias, lns, lnb, xf, xb,
                                                      s2, b2, out_attn, NBb);
    };

    init_k<<<512, 256, 0, stream>>>(x, MEMf, Yf, MEMb, Yb);

    // ----------------------------- encoder -----------------------------------
    for (int i = 0; i < NLAY; ++i) {
        run_self(MEMb, 0, 1, i, enc_qkv_b + i * 1536, enc_out_b + i * 512,
                 enc_ln1_s + i * 512, enc_ln1_b + i * 512, MEMf, MEMb);
        run_ffn(MEMb, 2, 3, i, enc_ff1_b + i * 2048, enc_ff2_b + i * 512,
                enc_ln2_s + i * 512, enc_ln2_b + i * 512, MEMf, MEMb,
                (i == NLAY - 1) ? 1 : 0, enc_norm_s, enc_norm_b);
    }

    // -------- hoisted decoder cross-attn K/V (all 6 layers, 1 dispatch) ------
    if (preconv) {
        gemm3(stream, false, true, MEMb, 512, wpre[6] + 512L * 512, 512,
              dec_ca_qkv_b + 512, KVCA, 1024, 1024L * 1024,
              1024, 1024, 512, 1.0f, 6, VTCA, 512,
              nullptr, 0, 0, 1536L * 512, 1536, 524288L);
    }

    // ----------------------------- decoder -----------------------------------
    for (int i = 0; i < NLAY; ++i) {
        run_self(Yb, 4, 5, i, dec_sa_qkv_b + i * 1536, dec_sa_out_b + i * 512,
                 dec_ln1_s + i * 512, dec_ln1_b + i * 512, Yf, Yb);

        if (preconv) {
            gemm3(stream, false, true, Yb, 512, W(6, i), 512, dec_ca_qkv_b + i * 1536,
                  QB, 512, 0, 1024, 512, 512, 1.0f, 1);
            attnp_k<<<dim3(64, 8), 128, 0, stream>>>(QB, 512,
                    KVCA + (long)i * 1024 * 1024, 1024, VTCA + (long)i * 524288,
                    W(7, i), (unsigned short*)SLAB);
        } else {
            gemm3(stream, false, true, Yb, 512, W(6, i), 512, dec_ca_qkv_b + i * 1536,
                  QKVb, 1536, 0, 1024, 1536, 512, 1.0f, 1, VT, 1024, MEMb, 512);
            attnp_k<<<dim3(64, 8), 128, 0, stream>>>(QKVb, 1536, QKVb + 512, 1536, VT,
                                                     W(7, i), (unsigned short*)SLAB);
        }
        ln_k<8, true, 0><<<256, 256, 0, stream>>>(Yf, SLAB, dec_ca_out_b + i * 512,
                                                  dec_ln2_s + i * 512, dec_ln2_b + i * 512,
                                                  Yf, Yb, nullptr, nullptr, nullptr, nullptr);

        run_ffn(Yb, 8, 9, i, dec_ff1_b + i * 2048, dec_ff2_b + i * 512,
                dec_ln3_s + i * 512, dec_ln3_b + i * 512, Yf, Yb,
                (i == NLAY - 1) ? 2 : 0, dec_norm_s, dec_norm_b);
    }

    // gram = n @ n^T
    gemm3(stream, false, false, NBb, 512, NBb, 512, nullptr,
          out_gram, 1024, 0, 1024, 1024, 512, 1.0f, 1);
}